// Round 1
// baseline (10222.275 us; speedup 1.0000x reference)
//
#include <hip/hip_runtime.h>
#include <hip/hip_bf16.h>

#ifndef LONG
typedef long long ll;
#endif

// ---------------- fill ----------------
__global__ void fill_kernel(float* __restrict__ p, float v, ll n) {
    ll i = (ll)blockIdx.x * blockDim.x + threadIdx.x;
    if (i < n) p[i] = v;
}

// ---------------- degree scatter: deg[col[e]] += w[e] ----------------
__global__ void scatter_deg_kernel(const int* __restrict__ col, const float* __restrict__ w,
                                   float* deg, ll E) {
    ll e = (ll)blockIdx.x * blockDim.x + threadIdx.x;
    if (e < E) atomicAdd(&deg[col[e]], w[e]);
}

// ---------------- dinv = 1/sqrt(deg) ----------------
__global__ void dinv_kernel(float* __restrict__ deg, int N) {
    int i = blockIdx.x * blockDim.x + threadIdx.x;
    if (i < N) {
        float d = deg[i];
        deg[i] = d > 0.0f ? 1.0f / sqrtf(d) : 0.0f;
    }
}

// ---------------- norm[e] = dinv[row]*w*dinv[col] ----------------
__global__ void norm_kernel(const int* __restrict__ row, const int* __restrict__ col,
                            const float* __restrict__ w, const float* __restrict__ dinv,
                            float* __restrict__ norm, ll E) {
    ll e = (ll)blockIdx.x * blockDim.x + threadIdx.x;
    if (e < E) norm[e] = dinv[row[e]] * w[e] * dinv[col[e]];
}

// ---------------- generic tiled GEMM: C[N,64] = A[N,K] @ B[K,64] ----------------
template <int K>
__global__ __launch_bounds__(128) void gemm_tile(const float* __restrict__ A,
                                                 const float* __restrict__ B,
                                                 float* __restrict__ C, int N) {
    const int BM = 128, BK = 16;
    __shared__ float As[BK][BM];  // transposed A tile
    __shared__ float Bs[BK][64];
    int tid = threadIdx.x;
    int bm = blockIdx.x * BM;
    int tx = tid & 7;    // col group: cols tx*8..tx*8+7
    int ty = tid >> 3;   // row group: rows ty*8..ty*8+7
    int lc = tid & 3;    // A loader: k-chunk (4 floats)
    int lr = tid >> 2;   // A loader: row 0..31
    int bk = tid >> 4;   // B loader: k row 0..7 (two passes)
    int bc = tid & 15;   // B loader: col chunk

    float acc[8][8];
#pragma unroll
    for (int i = 0; i < 8; i++)
#pragma unroll
        for (int j = 0; j < 8; j++) acc[i][j] = 0.0f;

    for (int k0 = 0; k0 < K; k0 += BK) {
        // load A tile 128x16 (transposed into As)
#pragma unroll
        for (int rr = 0; rr < 4; rr++) {
            int r = lr + rr * 32;
            int gr = bm + r;
            gr = gr < N ? gr : N - 1;
            const float4 av = *(const float4*)&A[(ll)gr * K + k0 + lc * 4];
            As[lc * 4 + 0][r] = av.x;
            As[lc * 4 + 1][r] = av.y;
            As[lc * 4 + 2][r] = av.z;
            As[lc * 4 + 3][r] = av.w;
        }
        // load B tile 16x64
#pragma unroll
        for (int pp = 0; pp < 2; pp++) {
            int kk = bk + pp * 8;
            *(float4*)&Bs[kk][bc * 4] = *(const float4*)&B[(ll)(k0 + kk) * 64 + bc * 4];
        }
        __syncthreads();
#pragma unroll
        for (int k = 0; k < BK; k++) {
            float a[8], b[8];
            *(float4*)&a[0] = *(const float4*)&As[k][ty * 8];
            *(float4*)&a[4] = *(const float4*)&As[k][ty * 8 + 4];
            *(float4*)&b[0] = *(const float4*)&Bs[k][tx * 8];
            *(float4*)&b[4] = *(const float4*)&Bs[k][tx * 8 + 4];
#pragma unroll
            for (int i = 0; i < 8; i++)
#pragma unroll
                for (int j = 0; j < 8; j++) acc[i][j] += a[i] * b[j];
        }
        __syncthreads();
    }
#pragma unroll
    for (int i = 0; i < 8; i++) {
        int gr = bm + ty * 8 + i;
        if (gr < N) {
            float4 v0 = make_float4(acc[i][0], acc[i][1], acc[i][2], acc[i][3]);
            float4 v1 = make_float4(acc[i][4], acc[i][5], acc[i][6], acc[i][7]);
            *(float4*)&C[(ll)gr * 64 + tx * 8] = v0;
            *(float4*)&C[(ll)gr * 64 + tx * 8 + 4] = v1;
        }
    }
}

// ---------------- 64-wide edge scatter: dst[col]+= coef*src[row], 4 lanes/edge x float4 ----------------
__global__ void scatter64_kernel(const int* __restrict__ row, const int* __restrict__ col,
                                 const float* __restrict__ coef, const float* __restrict__ src,
                                 float* dst, ll E) {
    ll t = (ll)blockIdx.x * blockDim.x + threadIdx.x;
    ll e = t >> 4;
    if (e >= E) return;
    int c4 = (threadIdx.x & 15) * 4;
    int r = row[e], c = col[e];
    float nm = coef[e];
    const float4 v = *(const float4*)&src[(ll)r * 64 + c4];
    float* dp = &dst[(ll)c * 64 + c4];
    atomicAdd(dp + 0, nm * v.x);
    atomicAdd(dp + 1, nm * v.y);
    atomicAdd(dp + 2, nm * v.z);
    atomicAdd(dp + 3, nm * v.w);
}

// ---------------- 16-wide edge scatter ----------------
__global__ void scatter16_kernel(const int* __restrict__ row, const int* __restrict__ col,
                                 const float* __restrict__ coef, const float* __restrict__ src,
                                 float* dst, ll E) {
    ll t = (ll)blockIdx.x * blockDim.x + threadIdx.x;
    ll e = t >> 2;
    if (e >= E) return;
    int c4 = (threadIdx.x & 3) * 4;
    int r = row[e], c = col[e];
    float nm = coef[e];
    const float4 v = *(const float4*)&src[(ll)r * 16 + c4];
    float* dp = &dst[(ll)c * 16 + c4];
    atomicAdd(dp + 0, nm * v.x);
    atomicAdd(dp + 1, nm * v.y);
    atomicAdd(dp + 2, nm * v.z);
    atomicAdd(dp + 3, nm * v.w);
}

// ---------------- GCN1 epilogue: xbuf = relu(out1 + h1*dinv^2 + b1) ----------------
__global__ void relu_bias_kernel(const float* __restrict__ out1, const float* __restrict__ h1,
                                 const float* __restrict__ dinv, const float* __restrict__ b1,
                                 float* __restrict__ xbuf, int N) {
    ll t = (ll)blockIdx.x * blockDim.x + threadIdx.x;
    if (t >= (ll)N * 64) return;
    int n = (int)(t >> 6);
    int j = (int)(t & 63);
    float d2 = dinv[n] * dinv[n];
    float v = out1[t] + h1[t] * d2 + b1[j];
    xbuf[t] = v > 0.0f ? v : 0.0f;
}

// ---------------- fused GRU cell (per node) ----------------
__global__ __launch_bounds__(256) void gru_kernel(float* x, const float* __restrict__ agg,
                                                  const float* __restrict__ Wih,
                                                  const float* __restrict__ Whh,
                                                  const float* __restrict__ bih,
                                                  const float* __restrict__ bhh, int N) {
    int n = blockIdx.x * blockDim.x + threadIdx.x;
    if (n >= N) return;
    float xr[64], ag[64];
    float* xp = x + (ll)n * 64;
    const float* ap = agg + (ll)n * 64;
#pragma unroll
    for (int k4 = 0; k4 < 16; k4++) {
        float4 xv = *(const float4*)&xp[k4 * 4];
        xr[k4 * 4 + 0] = xv.x; xr[k4 * 4 + 1] = xv.y; xr[k4 * 4 + 2] = xv.z; xr[k4 * 4 + 3] = xv.w;
        float4 av = *(const float4*)&ap[k4 * 4];
        ag[k4 * 4 + 0] = av.x; ag[k4 * 4 + 1] = av.y; ag[k4 * 4 + 2] = av.z; ag[k4 * 4 + 3] = av.w;
    }
    for (int j = 0; j < 64; j++) {
        float ir = bih[j], iz = bih[64 + j], in_ = bih[128 + j];
        float hr = bhh[j], hz = bhh[64 + j], hn = bhh[128 + j];
#pragma unroll
        for (int k = 0; k < 64; k++) {
            ir += ag[k] * Wih[j * 64 + k];
            iz += ag[k] * Wih[(64 + j) * 64 + k];
            in_ += ag[k] * Wih[(128 + j) * 64 + k];
            hr += xr[k] * Whh[j * 64 + k];
            hz += xr[k] * Whh[(64 + j) * 64 + k];
            hn += xr[k] * Whh[(128 + j) * 64 + k];
        }
        float r = 1.0f / (1.0f + expf(-(ir + hr)));
        float z = 1.0f / (1.0f + expf(-(iz + hz)));
        float ng = tanhf(in_ + r * hn);
        float xj = xp[j];  // reload to avoid dynamic register-array index
        xp[j] = (1.0f - z) * ng + z * xj;
    }
}

// ---------------- h2 = x @ W2  ([N,64]@[64,16]) ----------------
__global__ void gemm_w2_kernel(const float* __restrict__ x, const float* __restrict__ W2,
                               float* __restrict__ h2, int N) {
    ll t = (ll)blockIdx.x * blockDim.x + threadIdx.x;
    if (t >= (ll)N * 16) return;
    int n = (int)(t >> 4);
    int c = (int)(t & 15);
    float acc = 0.0f;
#pragma unroll
    for (int k = 0; k < 64; k++) acc += x[(ll)n * 64 + k] * W2[k * 16 + c];
    h2[t] = acc;
}

// ---------------- final: self loop + bias + log_softmax ----------------
__global__ void final_kernel(const float* __restrict__ out2, const float* __restrict__ h2,
                             const float* __restrict__ dinv, const float* __restrict__ b2,
                             float* __restrict__ out, int N) {
    int n = blockIdx.x * blockDim.x + threadIdx.x;
    if (n >= N) return;
    float d2 = dinv[n] * dinv[n];
    float v[16];
    float mx = -1e30f;
#pragma unroll
    for (int c = 0; c < 16; c++) {
        v[c] = out2[(ll)n * 16 + c] + h2[(ll)n * 16 + c] * d2 + b2[c];
        mx = fmaxf(mx, v[c]);
    }
    float s = 0.0f;
#pragma unroll
    for (int c = 0; c < 16; c++) s += expf(v[c] - mx);
    float l = logf(s) + mx;
#pragma unroll
    for (int c = 0; c < 16; c++) out[(ll)n * 16 + c] = v[c] - l;
}

extern "C" void kernel_launch(void* const* d_in, const int* in_sizes, int n_in,
                              void* d_out, int out_size, void* d_ws, size_t ws_size,
                              hipStream_t stream) {
    const float* x   = (const float*)d_in[0];
    const int*   ei  = (const int*)d_in[1];
    const float* ew  = (const float*)d_in[2];
    const float* W1  = (const float*)d_in[3];
    const float* b1  = (const float*)d_in[4];
    const float* Wg  = (const float*)d_in[5];
    const float* Wih = (const float*)d_in[6];
    const float* Whh = (const float*)d_in[7];
    const float* bih = (const float*)d_in[8];
    const float* bhh = (const float*)d_in[9];
    const float* W2  = (const float*)d_in[10];
    const float* b2  = (const float*)d_in[11];

    const int N = in_sizes[0] / 512;   // 100000
    const ll  E = in_sizes[2];         // 3200000
    const int* row = ei;
    const int* col = ei + E;

    float* ws = (float*)d_ws;
    ll o = 0;
    float* dinv = ws + o; o += (ll)N;        // deg -> dinv (in place)
    float* norm = ws + o; o += E;
    float* bufA = ws + o; o += (ll)N * 64;   // h1 / m / h2
    float* bufB = ws + o; o += (ll)N * 64;   // out1 / agg / out2
    float* xbuf = ws + o; o += (ll)N * 64;

    const int B = 256;
    dim3 blk(B);

    // degree + norm
    fill_kernel<<<(N + B - 1) / B, blk, 0, stream>>>(dinv, 1.0f, N);  // self-loop weight
    scatter_deg_kernel<<<(int)((E + B - 1) / B), blk, 0, stream>>>(col, ew, dinv, E);
    dinv_kernel<<<(N + B - 1) / B, blk, 0, stream>>>(dinv, N);
    norm_kernel<<<(int)((E + B - 1) / B), blk, 0, stream>>>(row, col, ew, dinv, norm, E);

    // GCN conv 1: h1 = x @ W1; scatter; relu(+bias+self loop)
    gemm_tile<512><<<(N + 127) / 128, dim3(128), 0, stream>>>(x, W1, bufA, N);
    fill_kernel<<<(int)(((ll)N * 64 + B - 1) / B), blk, 0, stream>>>(bufB, 0.0f, (ll)N * 64);
    scatter64_kernel<<<(int)((E * 16 + B - 1) / B), blk, 0, stream>>>(row, col, norm, bufA, bufB, E);
    relu_bias_kernel<<<(int)(((ll)N * 64 + B - 1) / B), blk, 0, stream>>>(bufB, bufA, dinv, b1, xbuf, N);

    // 2x GatedGraphConv layers
    for (int l = 0; l < 2; l++) {
        gemm_tile<64><<<(N + 127) / 128, dim3(128), 0, stream>>>(xbuf, Wg + (ll)l * 64 * 64, bufA, N);
        fill_kernel<<<(int)(((ll)N * 64 + B - 1) / B), blk, 0, stream>>>(bufB, 0.0f, (ll)N * 64);
        scatter64_kernel<<<(int)((E * 16 + B - 1) / B), blk, 0, stream>>>(row, col, ew, bufA, bufB, E);
        gru_kernel<<<(N + B - 1) / B, blk, 0, stream>>>(xbuf, bufB, Wih, Whh, bih, bhh, N);
    }

    // GCN conv 2 + log_softmax
    gemm_w2_kernel<<<(int)(((ll)N * 16 + B - 1) / B), blk, 0, stream>>>(xbuf, W2, bufA, N);
    fill_kernel<<<(int)(((ll)N * 16 + B - 1) / B), blk, 0, stream>>>(bufB, 0.0f, (ll)N * 16);
    scatter16_kernel<<<(int)((E * 4 + B - 1) / B), blk, 0, stream>>>(row, col, norm, bufA, bufB, E);
    final_kernel<<<(N + B - 1) / B, blk, 0, stream>>>(bufB, bufA, dinv, b2, (float*)d_out, N);
}

// Round 2
// 2582.395 us; speedup vs baseline: 3.9584x; 3.9584x over previous
//
#include <hip/hip_runtime.h>
#include <hip/hip_bf16.h>

typedef long long ll;

// ---------------- fills ----------------
__global__ void fill_f_kernel(float* __restrict__ p, float v, ll n) {
    ll i = (ll)blockIdx.x * blockDim.x + threadIdx.x;
    if (i < n) p[i] = v;
}
__global__ void fill_i_kernel(int* __restrict__ p, int v, ll n) {
    ll i = (ll)blockIdx.x * blockDim.x + threadIdx.x;
    if (i < n) p[i] = v;
}

// ---------------- histogram: cnt[col]++, deg[col]+=w ----------------
__global__ void hist_kernel(const int* __restrict__ col, const float* __restrict__ w,
                            int* cnt, float* deg, ll E) {
    ll e = (ll)blockIdx.x * blockDim.x + threadIdx.x;
    if (e < E) {
        int c = col[e];
        atomicAdd(&cnt[c], 1);
        atomicAdd(&deg[c], w[e]);
    }
}

// ---------------- dinv = 1/sqrt(deg) (in place) ----------------
__global__ void dinv_kernel(float* __restrict__ deg, int N) {
    int i = blockIdx.x * blockDim.x + threadIdx.x;
    if (i < N) {
        float d = deg[i];
        deg[i] = d > 0.0f ? 1.0f / sqrtf(d) : 0.0f;
    }
}

// ---------------- scan A: per-block sums of cnt ----------------
__global__ void scanA_kernel(const int* __restrict__ cnt, int* __restrict__ blockSums, int N) {
    __shared__ int s[256];
    int tid = threadIdx.x;
    int i = blockIdx.x * 256 + tid;
    s[tid] = (i < N) ? cnt[i] : 0;
    __syncthreads();
    for (int off = 128; off > 0; off >>= 1) {
        if (tid < off) s[tid] += s[tid + off];
        __syncthreads();
    }
    if (tid == 0) blockSums[blockIdx.x] = s[0];
}

// ---------------- scan B: exclusive scan of blockSums (single block, 512 thr) ----------------
__global__ void scanB_kernel(const int* __restrict__ blockSums, int* __restrict__ blockOff, int NB) {
    __shared__ int s[512];
    int tid = threadIdx.x;
    int v = (tid < NB) ? blockSums[tid] : 0;
    s[tid] = v;
    __syncthreads();
    for (int off = 1; off < 512; off <<= 1) {
        int t = (tid >= off) ? s[tid - off] : 0;
        __syncthreads();
        s[tid] += t;
        __syncthreads();
    }
    if (tid < NB) blockOff[tid] = s[tid] - v;  // exclusive
}

// ---------------- scan C: row_start/cursor = blockOff + excl-scan within block ----------------
__global__ void scanC_kernel(const int* __restrict__ cnt, const int* __restrict__ blockOff,
                             int* __restrict__ row_start, int* __restrict__ cursor, int N, int E) {
    __shared__ int s[256];
    int tid = threadIdx.x;
    int i = blockIdx.x * 256 + tid;
    int v = (i < N) ? cnt[i] : 0;
    s[tid] = v;
    __syncthreads();
    for (int off = 1; off < 256; off <<= 1) {
        int t = (tid >= off) ? s[tid - off] : 0;
        __syncthreads();
        s[tid] += t;
        __syncthreads();
    }
    if (i < N) {
        int excl = s[tid] - v + blockOff[blockIdx.x];
        row_start[i] = excl;
        cursor[i] = excl;
    }
    if (i == N) row_start[N] = E;
}

// ---------------- CSR build: place each edge at cursor[col]++ ----------------
__global__ void csr_build_kernel(const int* __restrict__ row, const int* __restrict__ col,
                                 const float* __restrict__ ew, const float* __restrict__ dinv,
                                 int* cursor, int* __restrict__ csr_src,
                                 float* __restrict__ csr_norm, float* __restrict__ csr_w, ll E) {
    ll e = (ll)blockIdx.x * blockDim.x + threadIdx.x;
    if (e >= E) return;
    int r = row[e], c = col[e];
    float w = ew[e];
    int pos = atomicAdd(&cursor[c], 1);
    csr_src[pos] = r;
    csr_w[pos] = w;
    csr_norm[pos] = dinv[r] * w * dinv[c];
}

// ---------------- tiled GEMM: C[N,64] = A[N,K] @ B[K,64] ----------------
template <int K>
__global__ __launch_bounds__(128) void gemm_tile(const float* __restrict__ A,
                                                 const float* __restrict__ B,
                                                 float* __restrict__ C, int N) {
    const int BM = 128, BK = 16;
    __shared__ float As[BK][BM];
    __shared__ float Bs[BK][64];
    int tid = threadIdx.x;
    int bm = blockIdx.x * BM;
    int tx = tid & 7;
    int ty = tid >> 3;
    int lc = tid & 3;
    int lr = tid >> 2;
    int bk = tid >> 4;
    int bc = tid & 15;

    float acc[8][8];
#pragma unroll
    for (int i = 0; i < 8; i++)
#pragma unroll
        for (int j = 0; j < 8; j++) acc[i][j] = 0.0f;

    for (int k0 = 0; k0 < K; k0 += BK) {
#pragma unroll
        for (int rr = 0; rr < 4; rr++) {
            int r = lr + rr * 32;
            int gr = bm + r;
            gr = gr < N ? gr : N - 1;
            const float4 av = *(const float4*)&A[(ll)gr * K + k0 + lc * 4];
            As[lc * 4 + 0][r] = av.x;
            As[lc * 4 + 1][r] = av.y;
            As[lc * 4 + 2][r] = av.z;
            As[lc * 4 + 3][r] = av.w;
        }
#pragma unroll
        for (int pp = 0; pp < 2; pp++) {
            int kk = bk + pp * 8;
            *(float4*)&Bs[kk][bc * 4] = *(const float4*)&B[(ll)(k0 + kk) * 64 + bc * 4];
        }
        __syncthreads();
#pragma unroll
        for (int k = 0; k < BK; k++) {
            float a[8], b[8];
            *(float4*)&a[0] = *(const float4*)&As[k][ty * 8];
            *(float4*)&a[4] = *(const float4*)&As[k][ty * 8 + 4];
            *(float4*)&b[0] = *(const float4*)&Bs[k][tx * 8];
            *(float4*)&b[4] = *(const float4*)&Bs[k][tx * 8 + 4];
#pragma unroll
            for (int i = 0; i < 8; i++)
#pragma unroll
                for (int j = 0; j < 8; j++) acc[i][j] += a[i] * b[j];
        }
        __syncthreads();
    }
#pragma unroll
    for (int i = 0; i < 8; i++) {
        int gr = bm + ty * 8 + i;
        if (gr < N) {
            float4 v0 = make_float4(acc[i][0], acc[i][1], acc[i][2], acc[i][3]);
            float4 v1 = make_float4(acc[i][4], acc[i][5], acc[i][6], acc[i][7]);
            *(float4*)&C[(ll)gr * 64 + tx * 8] = v0;
            *(float4*)&C[(ll)gr * 64 + tx * 8 + 4] = v1;
        }
    }
}

// ---------------- gather64 + GCN1 epilogue: xbuf = relu(sum + dinv^2*h1 + b1) ----------------
__global__ __launch_bounds__(256) void gather64_gcn1_kernel(
    const int* __restrict__ csr_src, const float* __restrict__ csr_norm,
    const int* __restrict__ row_start, const float* __restrict__ h1,
    const float* __restrict__ dinv, const float* __restrict__ b1,
    float* __restrict__ xbuf, int N) {
    int node = blockIdx.x * 4 + (threadIdx.x >> 6);
    if (node >= N) return;
    int lane = threadIdx.x & 63;
    int p = row_start[node], pe = row_start[node + 1];
    float dn = dinv[node];
    float acc = dn * dn * h1[(ll)node * 64 + lane];
    for (; p + 4 <= pe; p += 4) {
        int r0 = csr_src[p], r1 = csr_src[p + 1], r2 = csr_src[p + 2], r3 = csr_src[p + 3];
        float c0 = csr_norm[p], c1 = csr_norm[p + 1], c2 = csr_norm[p + 2], c3 = csr_norm[p + 3];
        acc += c0 * h1[(ll)r0 * 64 + lane];
        acc += c1 * h1[(ll)r1 * 64 + lane];
        acc += c2 * h1[(ll)r2 * 64 + lane];
        acc += c3 * h1[(ll)r3 * 64 + lane];
    }
    for (; p < pe; p++) acc += csr_norm[p] * h1[(ll)csr_src[p] * 64 + lane];
    float v = acc + b1[lane];
    xbuf[(ll)node * 64 + lane] = v > 0.0f ? v : 0.0f;
}

// ---------------- plain gather64 (GGC agg): dst = sum csr_w * src[csr_src] ----------------
__global__ __launch_bounds__(256) void gather64_kernel(
    const int* __restrict__ csr_src, const float* __restrict__ csr_w,
    const int* __restrict__ row_start, const float* __restrict__ src,
    float* __restrict__ dst, int N) {
    int node = blockIdx.x * 4 + (threadIdx.x >> 6);
    if (node >= N) return;
    int lane = threadIdx.x & 63;
    int p = row_start[node], pe = row_start[node + 1];
    float acc = 0.0f;
    for (; p + 4 <= pe; p += 4) {
        int r0 = csr_src[p], r1 = csr_src[p + 1], r2 = csr_src[p + 2], r3 = csr_src[p + 3];
        float c0 = csr_w[p], c1 = csr_w[p + 1], c2 = csr_w[p + 2], c3 = csr_w[p + 3];
        acc += c0 * src[(ll)r0 * 64 + lane];
        acc += c1 * src[(ll)r1 * 64 + lane];
        acc += c2 * src[(ll)r2 * 64 + lane];
        acc += c3 * src[(ll)r3 * 64 + lane];
    }
    for (; p < pe; p++) acc += csr_w[p] * src[(ll)csr_src[p] * 64 + lane];
    dst[(ll)node * 64 + lane] = acc;
}

// ---------------- fused GRU cell (per node) ----------------
__global__ __launch_bounds__(256) void gru_kernel(float* x, const float* __restrict__ agg,
                                                  const float* __restrict__ Wih,
                                                  const float* __restrict__ Whh,
                                                  const float* __restrict__ bih,
                                                  const float* __restrict__ bhh, int N) {
    int n = blockIdx.x * blockDim.x + threadIdx.x;
    if (n >= N) return;
    float xr[64], ag[64];
    float* xp = x + (ll)n * 64;
    const float* ap = agg + (ll)n * 64;
#pragma unroll
    for (int k4 = 0; k4 < 16; k4++) {
        float4 xv = *(const float4*)&xp[k4 * 4];
        xr[k4 * 4 + 0] = xv.x; xr[k4 * 4 + 1] = xv.y; xr[k4 * 4 + 2] = xv.z; xr[k4 * 4 + 3] = xv.w;
        float4 av = *(const float4*)&ap[k4 * 4];
        ag[k4 * 4 + 0] = av.x; ag[k4 * 4 + 1] = av.y; ag[k4 * 4 + 2] = av.z; ag[k4 * 4 + 3] = av.w;
    }
    for (int j = 0; j < 64; j++) {
        float ir = bih[j], iz = bih[64 + j], in_ = bih[128 + j];
        float hr = bhh[j], hz = bhh[64 + j], hn = bhh[128 + j];
#pragma unroll
        for (int k = 0; k < 64; k++) {
            ir += ag[k] * Wih[j * 64 + k];
            iz += ag[k] * Wih[(64 + j) * 64 + k];
            in_ += ag[k] * Wih[(128 + j) * 64 + k];
            hr += xr[k] * Whh[j * 64 + k];
            hz += xr[k] * Whh[(64 + j) * 64 + k];
            hn += xr[k] * Whh[(128 + j) * 64 + k];
        }
        float r = 1.0f / (1.0f + expf(-(ir + hr)));
        float z = 1.0f / (1.0f + expf(-(iz + hz)));
        float ng = tanhf(in_ + r * hn);
        float xj = xp[j];
        xp[j] = (1.0f - z) * ng + z * xj;
    }
}

// ---------------- h2 = x @ W2 ([N,64]@[64,16]) ----------------
__global__ void gemm_w2_kernel(const float* __restrict__ x, const float* __restrict__ W2,
                               float* __restrict__ h2, int N) {
    ll t = (ll)blockIdx.x * blockDim.x + threadIdx.x;
    if (t >= (ll)N * 16) return;
    int n = (int)(t >> 4);
    int c = (int)(t & 15);
    float acc = 0.0f;
#pragma unroll
    for (int k = 0; k < 64; k++) acc += x[(ll)n * 64 + k] * W2[k * 16 + c];
    h2[t] = acc;
}

// ---------------- gather16 + self-loop + bias + log_softmax (16 lanes/node) ----------------
__global__ __launch_bounds__(256) void gather16_final_kernel(
    const int* __restrict__ csr_src, const float* __restrict__ csr_norm,
    const int* __restrict__ row_start, const float* __restrict__ h2,
    const float* __restrict__ dinv, const float* __restrict__ b2,
    float* __restrict__ out, int N) {
    int node = blockIdx.x * 16 + (threadIdx.x >> 4);
    if (node >= N) return;  // whole 16-lane group exits together
    int lane = threadIdx.x & 15;
    int p = row_start[node], pe = row_start[node + 1];
    float dn = dinv[node];
    float acc = dn * dn * h2[(ll)node * 16 + lane];
    for (; p + 4 <= pe; p += 4) {
        int r0 = csr_src[p], r1 = csr_src[p + 1], r2 = csr_src[p + 2], r3 = csr_src[p + 3];
        float c0 = csr_norm[p], c1 = csr_norm[p + 1], c2 = csr_norm[p + 2], c3 = csr_norm[p + 3];
        acc += c0 * h2[(ll)r0 * 16 + lane];
        acc += c1 * h2[(ll)r1 * 16 + lane];
        acc += c2 * h2[(ll)r2 * 16 + lane];
        acc += c3 * h2[(ll)r3 * 16 + lane];
    }
    for (; p < pe; p++) acc += csr_norm[p] * h2[(ll)csr_src[p] * 16 + lane];
    float v = acc + b2[lane];
    // 16-lane log-softmax
    float mx = v;
    for (int m = 1; m < 16; m <<= 1) mx = fmaxf(mx, __shfl_xor(mx, m, 16));
    float ex = expf(v - mx);
    float sum = ex;
    for (int m = 1; m < 16; m <<= 1) sum += __shfl_xor(sum, m, 16);
    out[(ll)node * 16 + lane] = v - mx - logf(sum);
}

extern "C" void kernel_launch(void* const* d_in, const int* in_sizes, int n_in,
                              void* d_out, int out_size, void* d_ws, size_t ws_size,
                              hipStream_t stream) {
    const float* x   = (const float*)d_in[0];
    const int*   ei  = (const int*)d_in[1];
    const float* ew  = (const float*)d_in[2];
    const float* W1  = (const float*)d_in[3];
    const float* b1  = (const float*)d_in[4];
    const float* Wg  = (const float*)d_in[5];
    const float* Wih = (const float*)d_in[6];
    const float* Whh = (const float*)d_in[7];
    const float* bih = (const float*)d_in[8];
    const float* bhh = (const float*)d_in[9];
    const float* W2  = (const float*)d_in[10];
    const float* b2  = (const float*)d_in[11];

    const int N = in_sizes[0] / 512;   // 100000
    const ll  E = in_sizes[2];         // 3200000
    const int* row = ei;
    const int* col = ei + E;

    // ---- workspace carve ----
    char* base = (char*)d_ws;
    size_t off = 0;
    auto carveF = [&](ll n) { float* p = (float*)(base + off); off += (size_t)n * 4; return p; };
    auto carveI = [&](ll n) { int*   p = (int*)(base + off);   off += (size_t)n * 4; return p; };
    float* dinv     = carveF(N);
    float* bufA     = carveF((ll)N * 64);
    float* bufB     = carveF((ll)N * 64);
    float* xbuf     = carveF((ll)N * 64);
    float* csr_norm = carveF(E);
    float* csr_w    = carveF(E);
    int*   csr_src  = carveI(E);
    int*   row_st   = carveI(N + 1);
    int*   cursor   = carveI(N);
    int*   cnt      = carveI(N);
    int*   blkSums  = carveI(512);
    int*   blkOff   = carveI(512);
    (void)ws_size;

    const int B = 256;
    const int NB = (N + 255) / 256;  // 391 scan blocks (<=512)

    // ---- degree + CSR build ----
    fill_f_kernel<<<(N + B - 1) / B, B, 0, stream>>>(dinv, 1.0f, N);  // deg starts at self-loop 1
    fill_i_kernel<<<(N + B - 1) / B, B, 0, stream>>>(cnt, 0, N);
    hist_kernel<<<(int)((E + B - 1) / B), B, 0, stream>>>(col, ew, cnt, dinv, E);
    dinv_kernel<<<(N + B - 1) / B, B, 0, stream>>>(dinv, N);
    scanA_kernel<<<NB, 256, 0, stream>>>(cnt, blkSums, N);
    scanB_kernel<<<1, 512, 0, stream>>>(blkSums, blkOff, NB);
    scanC_kernel<<<NB, 256, 0, stream>>>(cnt, blkOff, row_st, cursor, N, (int)E);
    csr_build_kernel<<<(int)((E + B - 1) / B), B, 0, stream>>>(row, col, ew, dinv, cursor,
                                                               csr_src, csr_norm, csr_w, E);

    // ---- GCN conv 1 ----
    gemm_tile<512><<<(N + 127) / 128, 128, 0, stream>>>(x, W1, bufA, N);
    gather64_gcn1_kernel<<<(N + 3) / 4, 256, 0, stream>>>(csr_src, csr_norm, row_st, bufA,
                                                          dinv, b1, xbuf, N);

    // ---- 2x GatedGraphConv ----
    for (int l = 0; l < 2; l++) {
        gemm_tile<64><<<(N + 127) / 128, 128, 0, stream>>>(xbuf, Wg + (ll)l * 64 * 64, bufA, N);
        gather64_kernel<<<(N + 3) / 4, 256, 0, stream>>>(csr_src, csr_w, row_st, bufA, bufB, N);
        gru_kernel<<<(N + B - 1) / B, B, 0, stream>>>(xbuf, bufB, Wih, Whh, bih, bhh, N);
    }

    // ---- GCN conv 2 + log_softmax ----
    gemm_w2_kernel<<<(int)(((ll)N * 16 + B - 1) / B), B, 0, stream>>>(xbuf, W2, bufA, N);
    gather16_final_kernel<<<(N + 15) / 16, 256, 0, stream>>>(csr_src, csr_norm, row_st, bufA,
                                                             dinv, b2, (float*)d_out, N);
}

// Round 4
// 1610.659 us; speedup vs baseline: 6.3466x; 1.6033x over previous
//
#include <hip/hip_runtime.h>
#include <hip/hip_bf16.h>

typedef long long ll;

// ---------------- fills ----------------
__global__ void fill_f_kernel(float* __restrict__ p, float v, ll n) {
    ll i = (ll)blockIdx.x * blockDim.x + threadIdx.x;
    if (i < n) p[i] = v;
}
__global__ void fill_i_kernel(int* __restrict__ p, int v, ll n) {
    ll i = (ll)blockIdx.x * blockDim.x + threadIdx.x;
    if (i < n) p[i] = v;
}

// ---------------- histogram: cnt[col]++, deg[col]+=w ----------------
__global__ void hist_kernel(const int* __restrict__ col, const float* __restrict__ w,
                            int* cnt, float* deg, ll E) {
    ll e = (ll)blockIdx.x * blockDim.x + threadIdx.x;
    if (e < E) {
        int c = col[e];
        atomicAdd(&cnt[c], 1);
        atomicAdd(&deg[c], w[e]);
    }
}

// ---------------- dinv = 1/sqrt(deg) (in place) ----------------
__global__ void dinv_kernel(float* __restrict__ deg, int N) {
    int i = blockIdx.x * blockDim.x + threadIdx.x;
    if (i < N) {
        float d = deg[i];
        deg[i] = d > 0.0f ? 1.0f / sqrtf(d) : 0.0f;
    }
}

// ---------------- scan A: per-block sums of cnt ----------------
__global__ void scanA_kernel(const int* __restrict__ cnt, int* __restrict__ blockSums, int N) {
    __shared__ int s[256];
    int tid = threadIdx.x;
    int i = blockIdx.x * 256 + tid;
    s[tid] = (i < N) ? cnt[i] : 0;
    __syncthreads();
    for (int off = 128; off > 0; off >>= 1) {
        if (tid < off) s[tid] += s[tid + off];
        __syncthreads();
    }
    if (tid == 0) blockSums[blockIdx.x] = s[0];
}

// ---------------- scan B: exclusive scan of blockSums (single block, 512 thr) ----------------
__global__ void scanB_kernel(const int* __restrict__ blockSums, int* __restrict__ blockOff, int NB) {
    __shared__ int s[512];
    int tid = threadIdx.x;
    int v = (tid < NB) ? blockSums[tid] : 0;
    s[tid] = v;
    __syncthreads();
    for (int off = 1; off < 512; off <<= 1) {
        int t = (tid >= off) ? s[tid - off] : 0;
        __syncthreads();
        s[tid] += t;
        __syncthreads();
    }
    if (tid < NB) blockOff[tid] = s[tid] - v;  // exclusive
}

// ---------------- scan C: row_start/cursor = blockOff + excl-scan within block ----------------
__global__ void scanC_kernel(const int* __restrict__ cnt, const int* __restrict__ blockOff,
                             int* __restrict__ row_start, int* __restrict__ cursor, int N, int E) {
    __shared__ int s[256];
    int tid = threadIdx.x;
    int i = blockIdx.x * 256 + tid;
    int v = (i < N) ? cnt[i] : 0;
    s[tid] = v;
    __syncthreads();
    for (int off = 1; off < 256; off <<= 1) {
        int t = (tid >= off) ? s[tid - off] : 0;
        __syncthreads();
        s[tid] += t;
        __syncthreads();
    }
    if (i < N) {
        int excl = s[tid] - v + blockOff[blockIdx.x];
        row_start[i] = excl;
        cursor[i] = excl;
    }
    if (i == N) row_start[N] = E;
}

// ---------------- CSR build ----------------
__global__ void csr_build_kernel(const int* __restrict__ row, const int* __restrict__ col,
                                 const float* __restrict__ ew, const float* __restrict__ dinv,
                                 int* cursor, int* __restrict__ csr_src,
                                 float* __restrict__ csr_norm, float* __restrict__ csr_w, ll E) {
    ll e = (ll)blockIdx.x * blockDim.x + threadIdx.x;
    if (e >= E) return;
    int r = row[e], c = col[e];
    float w = ew[e];
    int pos = atomicAdd(&cursor[c], 1);
    csr_src[pos] = r;
    csr_w[pos] = w;
    csr_norm[pos] = dinv[r] * w * dinv[c];
}

// ---------------- weight transpose: WT[k*192+j] = W[j*64+k], W is [192,64] ----------------
// NOTE: 12288 is NOT a power of two -> must use subtraction, not &12287 (that was the R3 bug).
__global__ void wtrans_kernel(const float* __restrict__ Wih, const float* __restrict__ Whh,
                              float* __restrict__ WihT, float* __restrict__ WhhT) {
    int t = blockIdx.x * blockDim.x + threadIdx.x;  // 0..24575
    if (t >= 24576) return;
    int half = (t >= 12288) ? 1 : 0;
    int i = t - half * 12288;
    const float* src = half ? Whh : Wih;
    float* dst = half ? WhhT : WihT;
    int k = i / 192;
    int j = i - k * 192;
    dst[i] = src[j * 64 + k];
}

// ---------------- tiled GEMM: C[N,64] = A[N,K] @ B[K,64] ----------------
template <int K>
__global__ __launch_bounds__(128) void gemm_tile(const float* __restrict__ A,
                                                 const float* __restrict__ B,
                                                 float* __restrict__ C, int N) {
    const int BM = 128, BK = 16;
    __shared__ float As[BK][BM];
    __shared__ float Bs[BK][64];
    int tid = threadIdx.x;
    int bm = blockIdx.x * BM;
    int tx = tid & 7;
    int ty = tid >> 3;
    int lc = tid & 3;
    int lr = tid >> 2;
    int bk = tid >> 4;
    int bc = tid & 15;

    float acc[8][8];
#pragma unroll
    for (int i = 0; i < 8; i++)
#pragma unroll
        for (int j = 0; j < 8; j++) acc[i][j] = 0.0f;

    for (int k0 = 0; k0 < K; k0 += BK) {
#pragma unroll
        for (int rr = 0; rr < 4; rr++) {
            int r = lr + rr * 32;
            int gr = bm + r;
            gr = gr < N ? gr : N - 1;
            const float4 av = *(const float4*)&A[(ll)gr * K + k0 + lc * 4];
            As[lc * 4 + 0][r] = av.x;
            As[lc * 4 + 1][r] = av.y;
            As[lc * 4 + 2][r] = av.z;
            As[lc * 4 + 3][r] = av.w;
        }
#pragma unroll
        for (int pp = 0; pp < 2; pp++) {
            int kk = bk + pp * 8;
            *(float4*)&Bs[kk][bc * 4] = *(const float4*)&B[(ll)(k0 + kk) * 64 + bc * 4];
        }
        __syncthreads();
#pragma unroll
        for (int k = 0; k < BK; k++) {
            float a[8], b[8];
            *(float4*)&a[0] = *(const float4*)&As[k][ty * 8];
            *(float4*)&a[4] = *(const float4*)&As[k][ty * 8 + 4];
            *(float4*)&b[0] = *(const float4*)&Bs[k][tx * 8];
            *(float4*)&b[4] = *(const float4*)&Bs[k][tx * 8 + 4];
#pragma unroll
            for (int i = 0; i < 8; i++)
#pragma unroll
                for (int j = 0; j < 8; j++) acc[i][j] += a[i] * b[j];
        }
        __syncthreads();
    }
#pragma unroll
    for (int i = 0; i < 8; i++) {
        int gr = bm + ty * 8 + i;
        if (gr < N) {
            float4 v0 = make_float4(acc[i][0], acc[i][1], acc[i][2], acc[i][3]);
            float4 v1 = make_float4(acc[i][4], acc[i][5], acc[i][6], acc[i][7]);
            *(float4*)&C[(ll)gr * 64 + tx * 8] = v0;
            *(float4*)&C[(ll)gr * 64 + tx * 8 + 4] = v1;
        }
    }
}

// ---------------- gather64 + GCN1 epilogue ----------------
__global__ __launch_bounds__(256) void gather64_gcn1_kernel(
    const int* __restrict__ csr_src, const float* __restrict__ csr_norm,
    const int* __restrict__ row_start, const float* __restrict__ h1,
    const float* __restrict__ dinv, const float* __restrict__ b1,
    float* __restrict__ xbuf, int N) {
    int node = blockIdx.x * 4 + (threadIdx.x >> 6);
    if (node >= N) return;
    int lane = threadIdx.x & 63;
    int p = row_start[node], pe = row_start[node + 1];
    float dn = dinv[node];
    float acc = dn * dn * h1[(ll)node * 64 + lane];
    for (; p + 4 <= pe; p += 4) {
        int r0 = csr_src[p], r1 = csr_src[p + 1], r2 = csr_src[p + 2], r3 = csr_src[p + 3];
        float c0 = csr_norm[p], c1 = csr_norm[p + 1], c2 = csr_norm[p + 2], c3 = csr_norm[p + 3];
        acc += c0 * h1[(ll)r0 * 64 + lane];
        acc += c1 * h1[(ll)r1 * 64 + lane];
        acc += c2 * h1[(ll)r2 * 64 + lane];
        acc += c3 * h1[(ll)r3 * 64 + lane];
    }
    for (; p < pe; p++) acc += csr_norm[p] * h1[(ll)csr_src[p] * 64 + lane];
    float v = acc + b1[lane];
    xbuf[(ll)node * 64 + lane] = v > 0.0f ? v : 0.0f;
}

// ---------------- plain gather64 ----------------
__global__ __launch_bounds__(256) void gather64_kernel(
    const int* __restrict__ csr_src, const float* __restrict__ csr_w,
    const int* __restrict__ row_start, const float* __restrict__ src,
    float* __restrict__ dst, int N) {
    int node = blockIdx.x * 4 + (threadIdx.x >> 6);
    if (node >= N) return;
    int lane = threadIdx.x & 63;
    int p = row_start[node], pe = row_start[node + 1];
    float acc = 0.0f;
    for (; p + 4 <= pe; p += 4) {
        int r0 = csr_src[p], r1 = csr_src[p + 1], r2 = csr_src[p + 2], r3 = csr_src[p + 3];
        float c0 = csr_w[p], c1 = csr_w[p + 1], c2 = csr_w[p + 2], c3 = csr_w[p + 3];
        acc += c0 * src[(ll)r0 * 64 + lane];
        acc += c1 * src[(ll)r1 * 64 + lane];
        acc += c2 * src[(ll)r2 * 64 + lane];
        acc += c3 * src[(ll)r3 * 64 + lane];
    }
    for (; p < pe; p++) acc += csr_w[p] * src[(ll)csr_src[p] * 64 + lane];
    dst[(ll)node * 64 + lane] = acc;
}

// ---------------- fused GRU: gi = agg@WihT, gh = x@WhhT, gate, x updated in place ----------------
// Block: 64 nodes, 256 threads. Thread (rg=tid>>5, cg=tid&31) owns rows rg*8..+7, cols {2cg, 2cg+1}.
__global__ __launch_bounds__(256) void gru_fused_kernel(
    float* __restrict__ x, const float* __restrict__ agg,
    const float* __restrict__ WihT, const float* __restrict__ WhhT,
    const float* __restrict__ bih, const float* __restrict__ bhh, int N) {
    __shared__ float Aag[16][64];
    __shared__ float Axx[16][64];
    __shared__ float Bih[16][192];
    __shared__ float Bhh[16][192];

    int tid = threadIdx.x;
    int bm = blockIdx.x * 64;
    int rg = tid >> 5;        // 0..7 (8 rows each)
    int cg = tid & 31;        // 0..31 (2 cols each)
    int jb = cg * 2;

    int lm = tid >> 2;        // row 0..63
    int lkc = tid & 3;        // k-chunk 0..3

    float air[2][8], aiz[2][8], ain[2][8], ahr[2][8], ahz[2][8], ahn[2][8];
#pragma unroll
    for (int j = 0; j < 2; j++)
#pragma unroll
        for (int i = 0; i < 8; i++) {
            air[j][i] = 0.f; aiz[j][i] = 0.f; ain[j][i] = 0.f;
            ahr[j][i] = 0.f; ahz[j][i] = 0.f; ahn[j][i] = 0.f;
        }

    for (int kb = 0; kb < 4; kb++) {
        int k0 = kb * 16;
        int gr = bm + lm; gr = gr < N ? gr : N - 1;
        float4 va = *(const float4*)&agg[(ll)gr * 64 + k0 + lkc * 4];
        float4 vx = *(const float4*)&x[(ll)gr * 64 + k0 + lkc * 4];
        Aag[lkc * 4 + 0][lm] = va.x; Aag[lkc * 4 + 1][lm] = va.y;
        Aag[lkc * 4 + 2][lm] = va.z; Aag[lkc * 4 + 3][lm] = va.w;
        Axx[lkc * 4 + 0][lm] = vx.x; Axx[lkc * 4 + 1][lm] = vx.y;
        Axx[lkc * 4 + 2][lm] = vx.z; Axx[lkc * 4 + 3][lm] = vx.w;
#pragma unroll
        for (int p = 0; p < 3; p++) {
            int f = tid + p * 256;
            int br = f / 48, bc = f - br * 48;
            *(float4*)&Bih[br][bc * 4] = *(const float4*)&WihT[(ll)(k0 + br) * 192 + bc * 4];
            *(float4*)&Bhh[br][bc * 4] = *(const float4*)&WhhT[(ll)(k0 + br) * 192 + bc * 4];
        }
        __syncthreads();
#pragma unroll
        for (int k = 0; k < 16; k++) {
            float4 g0 = *(const float4*)&Aag[k][rg * 8];
            float4 g1 = *(const float4*)&Aag[k][rg * 8 + 4];
            float4 x0 = *(const float4*)&Axx[k][rg * 8];
            float4 x1 = *(const float4*)&Axx[k][rg * 8 + 4];
            float2 wir = *(const float2*)&Bih[k][jb];
            float2 wiz = *(const float2*)&Bih[k][64 + jb];
            float2 win = *(const float2*)&Bih[k][128 + jb];
            float2 whr = *(const float2*)&Bhh[k][jb];
            float2 whz = *(const float2*)&Bhh[k][64 + jb];
            float2 whn = *(const float2*)&Bhh[k][128 + jb];
            float ag[8] = {g0.x, g0.y, g0.z, g0.w, g1.x, g1.y, g1.z, g1.w};
            float ax[8] = {x0.x, x0.y, x0.z, x0.w, x1.x, x1.y, x1.z, x1.w};
#pragma unroll
            for (int i = 0; i < 8; i++) {
                air[0][i] += ag[i] * wir.x; air[1][i] += ag[i] * wir.y;
                aiz[0][i] += ag[i] * wiz.x; aiz[1][i] += ag[i] * wiz.y;
                ain[0][i] += ag[i] * win.x; ain[1][i] += ag[i] * win.y;
                ahr[0][i] += ax[i] * whr.x; ahr[1][i] += ax[i] * whr.y;
                ahz[0][i] += ax[i] * whz.x; ahz[1][i] += ax[i] * whz.y;
                ahn[0][i] += ax[i] * whn.x; ahn[1][i] += ax[i] * whn.y;
            }
        }
        __syncthreads();
    }

    float bi_r0 = bih[jb], bi_r1 = bih[jb + 1];
    float bi_z0 = bih[64 + jb], bi_z1 = bih[64 + jb + 1];
    float bi_n0 = bih[128 + jb], bi_n1 = bih[128 + jb + 1];
    float bh_r0 = bhh[jb], bh_r1 = bhh[jb + 1];
    float bh_z0 = bhh[64 + jb], bh_z1 = bhh[64 + jb + 1];
    float bh_n0 = bhh[128 + jb], bh_n1 = bhh[128 + jb + 1];
#pragma unroll
    for (int i = 0; i < 8; i++) {
        int node = bm + rg * 8 + i;
        if (node >= N) break;
        float2 xo = *(const float2*)&x[(ll)node * 64 + jb];
        float r0 = 1.f / (1.f + expf(-(air[0][i] + bi_r0 + ahr[0][i] + bh_r0)));
        float z0 = 1.f / (1.f + expf(-(aiz[0][i] + bi_z0 + ahz[0][i] + bh_z0)));
        float n0 = tanhf(ain[0][i] + bi_n0 + r0 * (ahn[0][i] + bh_n0));
        float r1 = 1.f / (1.f + expf(-(air[1][i] + bi_r1 + ahr[1][i] + bh_r1)));
        float z1 = 1.f / (1.f + expf(-(aiz[1][i] + bi_z1 + ahz[1][i] + bh_z1)));
        float n1 = tanhf(ain[1][i] + bi_n1 + r1 * (ahn[1][i] + bh_n1));
        float2 xn;
        xn.x = (1.f - z0) * n0 + z0 * xo.x;
        xn.y = (1.f - z1) * n1 + z1 * xo.y;
        *(float2*)&x[(ll)node * 64 + jb] = xn;
    }
}

// ---------------- h2 = x @ W2 ([N,64]@[64,16]) ----------------
__global__ void gemm_w2_kernel(const float* __restrict__ x, const float* __restrict__ W2,
                               float* __restrict__ h2, int N) {
    ll t = (ll)blockIdx.x * blockDim.x + threadIdx.x;
    if (t >= (ll)N * 16) return;
    int n = (int)(t >> 4);
    int c = (int)(t & 15);
    float acc = 0.0f;
#pragma unroll
    for (int k = 0; k < 64; k++) acc += x[(ll)n * 64 + k] * W2[k * 16 + c];
    h2[t] = acc;
}

// ---------------- gather16 + self-loop + bias + log_softmax ----------------
__global__ __launch_bounds__(256) void gather16_final_kernel(
    const int* __restrict__ csr_src, const float* __restrict__ csr_norm,
    const int* __restrict__ row_start, const float* __restrict__ h2,
    const float* __restrict__ dinv, const float* __restrict__ b2,
    float* __restrict__ out, int N) {
    int node = blockIdx.x * 16 + (threadIdx.x >> 4);
    if (node >= N) return;
    int lane = threadIdx.x & 15;
    int p = row_start[node], pe = row_start[node + 1];
    float dn = dinv[node];
    float acc = dn * dn * h2[(ll)node * 16 + lane];
    for (; p + 4 <= pe; p += 4) {
        int r0 = csr_src[p], r1 = csr_src[p + 1], r2 = csr_src[p + 2], r3 = csr_src[p + 3];
        float c0 = csr_norm[p], c1 = csr_norm[p + 1], c2 = csr_norm[p + 2], c3 = csr_norm[p + 3];
        acc += c0 * h2[(ll)r0 * 16 + lane];
        acc += c1 * h2[(ll)r1 * 16 + lane];
        acc += c2 * h2[(ll)r2 * 16 + lane];
        acc += c3 * h2[(ll)r3 * 16 + lane];
    }
    for (; p < pe; p++) acc += csr_norm[p] * h2[(ll)csr_src[p] * 16 + lane];
    float v = acc + b2[lane];
    float mx = v;
    for (int m = 1; m < 16; m <<= 1) mx = fmaxf(mx, __shfl_xor(mx, m, 16));
    float ex = expf(v - mx);
    float sum = ex;
    for (int m = 1; m < 16; m <<= 1) sum += __shfl_xor(sum, m, 16);
    out[(ll)node * 16 + lane] = v - mx - logf(sum);
}

extern "C" void kernel_launch(void* const* d_in, const int* in_sizes, int n_in,
                              void* d_out, int out_size, void* d_ws, size_t ws_size,
                              hipStream_t stream) {
    const float* x   = (const float*)d_in[0];
    const int*   ei  = (const int*)d_in[1];
    const float* ew  = (const float*)d_in[2];
    const float* W1  = (const float*)d_in[3];
    const float* b1  = (const float*)d_in[4];
    const float* Wg  = (const float*)d_in[5];
    const float* Wih = (const float*)d_in[6];
    const float* Whh = (const float*)d_in[7];
    const float* bih = (const float*)d_in[8];
    const float* bhh = (const float*)d_in[9];
    const float* W2  = (const float*)d_in[10];
    const float* b2  = (const float*)d_in[11];

    const int N = in_sizes[0] / 512;   // 100000
    const ll  E = in_sizes[2];         // 3200000
    const int* row = ei;
    const int* col = ei + E;

    // ---- workspace carve ----
    char* base = (char*)d_ws;
    size_t off = 0;
    auto carveF = [&](ll n) { float* p = (float*)(base + off); off += (size_t)n * 4; return p; };
    auto carveI = [&](ll n) { int*   p = (int*)(base + off);   off += (size_t)n * 4; return p; };
    float* dinv     = carveF(N);
    float* bufA     = carveF((ll)N * 64);
    float* bufB     = carveF((ll)N * 64);
    float* xbuf     = carveF((ll)N * 64);
    float* csr_norm = carveF(E);
    float* csr_w    = carveF(E);
    int*   csr_src  = carveI(E);
    int*   row_st   = carveI(N + 1);
    int*   cursor   = carveI(N);
    int*   cnt      = carveI(N);
    int*   blkSums  = carveI(512);
    int*   blkOff   = carveI(512);
    float* WihT     = carveF(12288);
    float* WhhT     = carveF(12288);
    (void)ws_size;

    const int B = 256;
    const int NB = (N + 255) / 256;

    // ---- degree + CSR build + weight transpose ----
    fill_f_kernel<<<(N + B - 1) / B, B, 0, stream>>>(dinv, 1.0f, N);
    fill_i_kernel<<<(N + B - 1) / B, B, 0, stream>>>(cnt, 0, N);
    hist_kernel<<<(int)((E + B - 1) / B), B, 0, stream>>>(col, ew, cnt, dinv, E);
    dinv_kernel<<<(N + B - 1) / B, B, 0, stream>>>(dinv, N);
    scanA_kernel<<<NB, 256, 0, stream>>>(cnt, blkSums, N);
    scanB_kernel<<<1, 512, 0, stream>>>(blkSums, blkOff, NB);
    scanC_kernel<<<NB, 256, 0, stream>>>(cnt, blkOff, row_st, cursor, N, (int)E);
    csr_build_kernel<<<(int)((E + B - 1) / B), B, 0, stream>>>(row, col, ew, dinv, cursor,
                                                               csr_src, csr_norm, csr_w, E);
    wtrans_kernel<<<(24576 + B - 1) / B, B, 0, stream>>>(Wih, Whh, WihT, WhhT);

    // ---- GCN conv 1 ----
    gemm_tile<512><<<(N + 127) / 128, 128, 0, stream>>>(x, W1, bufA, N);
    gather64_gcn1_kernel<<<(N + 3) / 4, 256, 0, stream>>>(csr_src, csr_norm, row_st, bufA,
                                                          dinv, b1, xbuf, N);

    // ---- 2x GatedGraphConv ----
    for (int l = 0; l < 2; l++) {
        gemm_tile<64><<<(N + 127) / 128, 128, 0, stream>>>(xbuf, Wg + (ll)l * 64 * 64, bufA, N);
        gather64_kernel<<<(N + 3) / 4, 256, 0, stream>>>(csr_src, csr_w, row_st, bufA, bufB, N);
        gru_fused_kernel<<<(N + 63) / 64, 256, 0, stream>>>(xbuf, bufB, WihT, WhhT, bih, bhh, N);
    }

    // ---- GCN conv 2 + log_softmax ----
    gemm_w2_kernel<<<(int)(((ll)N * 16 + B - 1) / B), B, 0, stream>>>(xbuf, W2, bufA, N);
    gather16_final_kernel<<<(N + 15) / 16, 256, 0, stream>>>(csr_src, csr_norm, row_st, bufA,
                                                             dinv, b2, (float*)d_out, N);
}

// Round 5
// 1337.187 us; speedup vs baseline: 7.6446x; 1.2045x over previous
//
#include <hip/hip_runtime.h>
#include <hip/hip_bf16.h>

typedef long long ll;

// ---------------- fills ----------------
__global__ void fill_i_kernel(int* __restrict__ p, int v, ll n) {
    ll i = (ll)blockIdx.x * blockDim.x + threadIdx.x;
    if (i < n) p[i] = v;
}

// ---------------- hist+rank: rank[e] = cnt[col[e]]++  (ONE atomic per edge) ----------------
__global__ void hist_rank_kernel(const int* __restrict__ col, int* cnt,
                                 int* __restrict__ rank, ll E) {
    ll e = (ll)blockIdx.x * blockDim.x + threadIdx.x;
    if (e < E) rank[e] = atomicAdd(&cnt[col[e]], 1);
}

// ---------------- scan A: per-block sums of cnt ----------------
__global__ void scanA_kernel(const int* __restrict__ cnt, int* __restrict__ blockSums, int N) {
    __shared__ int s[256];
    int tid = threadIdx.x;
    int i = blockIdx.x * 256 + tid;
    s[tid] = (i < N) ? cnt[i] : 0;
    __syncthreads();
    for (int off = 128; off > 0; off >>= 1) {
        if (tid < off) s[tid] += s[tid + off];
        __syncthreads();
    }
    if (tid == 0) blockSums[blockIdx.x] = s[0];
}

// ---------------- scan B: exclusive scan of blockSums (single block, 512 thr) ----------------
__global__ void scanB_kernel(const int* __restrict__ blockSums, int* __restrict__ blockOff, int NB) {
    __shared__ int s[512];
    int tid = threadIdx.x;
    int v = (tid < NB) ? blockSums[tid] : 0;
    s[tid] = v;
    __syncthreads();
    for (int off = 1; off < 512; off <<= 1) {
        int t = (tid >= off) ? s[tid - off] : 0;
        __syncthreads();
        s[tid] += t;
        __syncthreads();
    }
    if (tid < NB) blockOff[tid] = s[tid] - v;  // exclusive
}

// ---------------- scan C: row_start = blockOff + excl-scan within block ----------------
__global__ void scanC_kernel(const int* __restrict__ cnt, const int* __restrict__ blockOff,
                             int* __restrict__ row_start, int N, int E) {
    __shared__ int s[256];
    int tid = threadIdx.x;
    int i = blockIdx.x * 256 + tid;
    int v = (i < N) ? cnt[i] : 0;
    s[tid] = v;
    __syncthreads();
    for (int off = 1; off < 256; off <<= 1) {
        int t = (tid >= off) ? s[tid - off] : 0;
        __syncthreads();
        s[tid] += t;
        __syncthreads();
    }
    if (i < N) row_start[i] = s[tid] - v + blockOff[blockIdx.x];
    if (i == N) row_start[N] = E;
}

// ---------------- placement (no atomics): csr_sw[row_st[col]+rank] = {src, bits(w)} ----------------
__global__ void place_kernel(const int* __restrict__ row, const int* __restrict__ col,
                             const float* __restrict__ ew, const int* __restrict__ rank,
                             const int* __restrict__ row_st, int2* __restrict__ csr_sw, ll E) {
    ll e = (ll)blockIdx.x * blockDim.x + threadIdx.x;
    if (e >= E) return;
    int c = col[e];
    int pos = row_st[c] + rank[e];
    csr_sw[pos] = make_int2(row[e], __float_as_int(ew[e]));
}

// ---------------- deg from CSR (no atomics): deg[n] = 1 + sum w ----------------
__global__ void deg_kernel(const int2* __restrict__ csr_sw, const int* __restrict__ row_st,
                           float* __restrict__ deg, int N) {
    int n = blockIdx.x * blockDim.x + threadIdx.x;
    if (n >= N) return;
    int p = row_st[n], pe = row_st[n + 1];
    float d = 1.0f;  // self-loop weight
    for (; p < pe; p++) d += __int_as_float(csr_sw[p].y);
    deg[n] = d;
}

// ---------------- dinv = 1/sqrt(deg) (in place) ----------------
__global__ void dinv_kernel(float* __restrict__ deg, int N) {
    int i = blockIdx.x * blockDim.x + threadIdx.x;
    if (i < N) {
        float d = deg[i];
        deg[i] = d > 0.0f ? 1.0f / sqrtf(d) : 0.0f;
    }
}

// ---------------- weight transpose: WT[k*192+j] = W[j*64+k], W is [192,64] ----------------
// NOTE: 12288 is NOT a power of two -> subtraction, not &12287 (R3 bug).
__global__ void wtrans_kernel(const float* __restrict__ Wih, const float* __restrict__ Whh,
                              float* __restrict__ WihT, float* __restrict__ WhhT) {
    int t = blockIdx.x * blockDim.x + threadIdx.x;  // 0..24575
    if (t >= 24576) return;
    int half = (t >= 12288) ? 1 : 0;
    int i = t - half * 12288;
    const float* src = half ? Whh : Wih;
    float* dst = half ? WhhT : WihT;
    int k = i / 192;
    int j = i - k * 192;
    dst[i] = src[j * 64 + k];
}

// ---------------- tiled GEMM: C[N,64] = A[N,K] @ B[K,64] ----------------
template <int K>
__global__ __launch_bounds__(128) void gemm_tile(const float* __restrict__ A,
                                                 const float* __restrict__ B,
                                                 float* __restrict__ C, int N) {
    const int BM = 128, BK = 16;
    __shared__ float As[BK][BM];
    __shared__ float Bs[BK][64];
    int tid = threadIdx.x;
    int bm = blockIdx.x * BM;
    int tx = tid & 7;
    int ty = tid >> 3;
    int lc = tid & 3;
    int lr = tid >> 2;
    int bk = tid >> 4;
    int bc = tid & 15;

    float acc[8][8];
#pragma unroll
    for (int i = 0; i < 8; i++)
#pragma unroll
        for (int j = 0; j < 8; j++) acc[i][j] = 0.0f;

    for (int k0 = 0; k0 < K; k0 += BK) {
#pragma unroll
        for (int rr = 0; rr < 4; rr++) {
            int r = lr + rr * 32;
            int gr = bm + r;
            gr = gr < N ? gr : N - 1;
            const float4 av = *(const float4*)&A[(ll)gr * K + k0 + lc * 4];
            As[lc * 4 + 0][r] = av.x;
            As[lc * 4 + 1][r] = av.y;
            As[lc * 4 + 2][r] = av.z;
            As[lc * 4 + 3][r] = av.w;
        }
#pragma unroll
        for (int pp = 0; pp < 2; pp++) {
            int kk = bk + pp * 8;
            *(float4*)&Bs[kk][bc * 4] = *(const float4*)&B[(ll)(k0 + kk) * 64 + bc * 4];
        }
        __syncthreads();
#pragma unroll
        for (int k = 0; k < BK; k++) {
            float a[8], b[8];
            *(float4*)&a[0] = *(const float4*)&As[k][ty * 8];
            *(float4*)&a[4] = *(const float4*)&As[k][ty * 8 + 4];
            *(float4*)&b[0] = *(const float4*)&Bs[k][tx * 8];
            *(float4*)&b[4] = *(const float4*)&Bs[k][tx * 8 + 4];
#pragma unroll
            for (int i = 0; i < 8; i++)
#pragma unroll
                for (int j = 0; j < 8; j++) acc[i][j] += a[i] * b[j];
        }
        __syncthreads();
    }
#pragma unroll
    for (int i = 0; i < 8; i++) {
        int gr = bm + ty * 8 + i;
        if (gr < N) {
            float4 v0 = make_float4(acc[i][0], acc[i][1], acc[i][2], acc[i][3]);
            float4 v1 = make_float4(acc[i][4], acc[i][5], acc[i][6], acc[i][7]);
            *(float4*)&C[(ll)gr * 64 + tx * 8] = v0;
            *(float4*)&C[(ll)gr * 64 + tx * 8 + 4] = v1;
        }
    }
}

// ---------------- gather64 + GCN1 epilogue (norm computed on the fly) ----------------
__global__ __launch_bounds__(256) void gather64_gcn1_kernel(
    const int2* __restrict__ csr_sw, const int* __restrict__ row_start,
    const float* __restrict__ h1, const float* __restrict__ dinv,
    const float* __restrict__ b1, float* __restrict__ xbuf, int N) {
    int node = blockIdx.x * 4 + (threadIdx.x >> 6);
    if (node >= N) return;
    int lane = threadIdx.x & 63;
    int p = row_start[node], pe = row_start[node + 1];
    float dn = dinv[node];
    float acc = dn * dn * h1[(ll)node * 64 + lane];
    for (; p + 4 <= pe; p += 4) {
        int2 s0 = csr_sw[p], s1 = csr_sw[p + 1], s2 = csr_sw[p + 2], s3 = csr_sw[p + 3];
        float c0 = dn * dinv[s0.x] * __int_as_float(s0.y);
        float c1 = dn * dinv[s1.x] * __int_as_float(s1.y);
        float c2 = dn * dinv[s2.x] * __int_as_float(s2.y);
        float c3 = dn * dinv[s3.x] * __int_as_float(s3.y);
        acc += c0 * h1[(ll)s0.x * 64 + lane];
        acc += c1 * h1[(ll)s1.x * 64 + lane];
        acc += c2 * h1[(ll)s2.x * 64 + lane];
        acc += c3 * h1[(ll)s3.x * 64 + lane];
    }
    for (; p < pe; p++) {
        int2 s = csr_sw[p];
        acc += dn * dinv[s.x] * __int_as_float(s.y) * h1[(ll)s.x * 64 + lane];
    }
    float v = acc + b1[lane];
    xbuf[(ll)node * 64 + lane] = v > 0.0f ? v : 0.0f;
}

// ---------------- plain gather64 (GGC agg) ----------------
__global__ __launch_bounds__(256) void gather64_kernel(
    const int2* __restrict__ csr_sw, const int* __restrict__ row_start,
    const float* __restrict__ src, float* __restrict__ dst, int N) {
    int node = blockIdx.x * 4 + (threadIdx.x >> 6);
    if (node >= N) return;
    int lane = threadIdx.x & 63;
    int p = row_start[node], pe = row_start[node + 1];
    float acc = 0.0f;
    for (; p + 4 <= pe; p += 4) {
        int2 s0 = csr_sw[p], s1 = csr_sw[p + 1], s2 = csr_sw[p + 2], s3 = csr_sw[p + 3];
        acc += __int_as_float(s0.y) * src[(ll)s0.x * 64 + lane];
        acc += __int_as_float(s1.y) * src[(ll)s1.x * 64 + lane];
        acc += __int_as_float(s2.y) * src[(ll)s2.x * 64 + lane];
        acc += __int_as_float(s3.y) * src[(ll)s3.x * 64 + lane];
    }
    for (; p < pe; p++) {
        int2 s = csr_sw[p];
        acc += __int_as_float(s.y) * src[(ll)s.x * 64 + lane];
    }
    dst[(ll)node * 64 + lane] = acc;
}

// ---------------- fused GRU (unchanged from R4) ----------------
__global__ __launch_bounds__(256) void gru_fused_kernel(
    float* __restrict__ x, const float* __restrict__ agg,
    const float* __restrict__ WihT, const float* __restrict__ WhhT,
    const float* __restrict__ bih, const float* __restrict__ bhh, int N) {
    __shared__ float Aag[16][64];
    __shared__ float Axx[16][64];
    __shared__ float Bih[16][192];
    __shared__ float Bhh[16][192];

    int tid = threadIdx.x;
    int bm = blockIdx.x * 64;
    int rg = tid >> 5;
    int cg = tid & 31;
    int jb = cg * 2;
    int lm = tid >> 2;
    int lkc = tid & 3;

    float air[2][8], aiz[2][8], ain[2][8], ahr[2][8], ahz[2][8], ahn[2][8];
#pragma unroll
    for (int j = 0; j < 2; j++)
#pragma unroll
        for (int i = 0; i < 8; i++) {
            air[j][i] = 0.f; aiz[j][i] = 0.f; ain[j][i] = 0.f;
            ahr[j][i] = 0.f; ahz[j][i] = 0.f; ahn[j][i] = 0.f;
        }

    for (int kb = 0; kb < 4; kb++) {
        int k0 = kb * 16;
        int gr = bm + lm; gr = gr < N ? gr : N - 1;
        float4 va = *(const float4*)&agg[(ll)gr * 64 + k0 + lkc * 4];
        float4 vx = *(const float4*)&x[(ll)gr * 64 + k0 + lkc * 4];
        Aag[lkc * 4 + 0][lm] = va.x; Aag[lkc * 4 + 1][lm] = va.y;
        Aag[lkc * 4 + 2][lm] = va.z; Aag[lkc * 4 + 3][lm] = va.w;
        Axx[lkc * 4 + 0][lm] = vx.x; Axx[lkc * 4 + 1][lm] = vx.y;
        Axx[lkc * 4 + 2][lm] = vx.z; Axx[lkc * 4 + 3][lm] = vx.w;
#pragma unroll
        for (int p = 0; p < 3; p++) {
            int f = tid + p * 256;
            int br = f / 48, bc = f - br * 48;
            *(float4*)&Bih[br][bc * 4] = *(const float4*)&WihT[(ll)(k0 + br) * 192 + bc * 4];
            *(float4*)&Bhh[br][bc * 4] = *(const float4*)&WhhT[(ll)(k0 + br) * 192 + bc * 4];
        }
        __syncthreads();
#pragma unroll
        for (int k = 0; k < 16; k++) {
            float4 g0 = *(const float4*)&Aag[k][rg * 8];
            float4 g1 = *(const float4*)&Aag[k][rg * 8 + 4];
            float4 x0 = *(const float4*)&Axx[k][rg * 8];
            float4 x1 = *(const float4*)&Axx[k][rg * 8 + 4];
            float2 wir = *(const float2*)&Bih[k][jb];
            float2 wiz = *(const float2*)&Bih[k][64 + jb];
            float2 win = *(const float2*)&Bih[k][128 + jb];
            float2 whr = *(const float2*)&Bhh[k][jb];
            float2 whz = *(const float2*)&Bhh[k][64 + jb];
            float2 whn = *(const float2*)&Bhh[k][128 + jb];
            float ag[8] = {g0.x, g0.y, g0.z, g0.w, g1.x, g1.y, g1.z, g1.w};
            float ax[8] = {x0.x, x0.y, x0.z, x0.w, x1.x, x1.y, x1.z, x1.w};
#pragma unroll
            for (int i = 0; i < 8; i++) {
                air[0][i] += ag[i] * wir.x; air[1][i] += ag[i] * wir.y;
                aiz[0][i] += ag[i] * wiz.x; aiz[1][i] += ag[i] * wiz.y;
                ain[0][i] += ag[i] * win.x; ain[1][i] += ag[i] * win.y;
                ahr[0][i] += ax[i] * whr.x; ahr[1][i] += ax[i] * whr.y;
                ahz[0][i] += ax[i] * whz.x; ahz[1][i] += ax[i] * whz.y;
                ahn[0][i] += ax[i] * whn.x; ahn[1][i] += ax[i] * whn.y;
            }
        }
        __syncthreads();
    }

    float bi_r0 = bih[jb], bi_r1 = bih[jb + 1];
    float bi_z0 = bih[64 + jb], bi_z1 = bih[64 + jb + 1];
    float bi_n0 = bih[128 + jb], bi_n1 = bih[128 + jb + 1];
    float bh_r0 = bhh[jb], bh_r1 = bhh[jb + 1];
    float bh_z0 = bhh[64 + jb], bh_z1 = bhh[64 + jb + 1];
    float bh_n0 = bhh[128 + jb], bh_n1 = bhh[128 + jb + 1];
#pragma unroll
    for (int i = 0; i < 8; i++) {
        int node = bm + rg * 8 + i;
        if (node >= N) break;
        float2 xo = *(const float2*)&x[(ll)node * 64 + jb];
        float r0 = 1.f / (1.f + expf(-(air[0][i] + bi_r0 + ahr[0][i] + bh_r0)));
        float z0 = 1.f / (1.f + expf(-(aiz[0][i] + bi_z0 + ahz[0][i] + bh_z0)));
        float n0 = tanhf(ain[0][i] + bi_n0 + r0 * (ahn[0][i] + bh_n0));
        float r1 = 1.f / (1.f + expf(-(air[1][i] + bi_r1 + ahr[1][i] + bh_r1)));
        float z1 = 1.f / (1.f + expf(-(aiz[1][i] + bi_z1 + ahz[1][i] + bh_z1)));
        float n1 = tanhf(ain[1][i] + bi_n1 + r1 * (ahn[1][i] + bh_n1));
        float2 xn;
        xn.x = (1.f - z0) * n0 + z0 * xo.x;
        xn.y = (1.f - z1) * n1 + z1 * xo.y;
        *(float2*)&x[(ll)node * 64 + jb] = xn;
    }
}

// ---------------- h2 = x @ W2 ([N,64]@[64,16]) ----------------
__global__ void gemm_w2_kernel(const float* __restrict__ x, const float* __restrict__ W2,
                               float* __restrict__ h2, int N) {
    ll t = (ll)blockIdx.x * blockDim.x + threadIdx.x;
    if (t >= (ll)N * 16) return;
    int n = (int)(t >> 4);
    int c = (int)(t & 15);
    float acc = 0.0f;
#pragma unroll
    for (int k = 0; k < 64; k++) acc += x[(ll)n * 64 + k] * W2[k * 16 + c];
    h2[t] = acc;
}

// ---------------- gather16 + self-loop + bias + log_softmax (norm on the fly) ----------------
__global__ __launch_bounds__(256) void gather16_final_kernel(
    const int2* __restrict__ csr_sw, const int* __restrict__ row_start,
    const float* __restrict__ h2, const float* __restrict__ dinv,
    const float* __restrict__ b2, float* __restrict__ out, int N) {
    int node = blockIdx.x * 16 + (threadIdx.x >> 4);
    if (node >= N) return;
    int lane = threadIdx.x & 15;
    int p = row_start[node], pe = row_start[node + 1];
    float dn = dinv[node];
    float acc = dn * dn * h2[(ll)node * 16 + lane];
    for (; p + 4 <= pe; p += 4) {
        int2 s0 = csr_sw[p], s1 = csr_sw[p + 1], s2 = csr_sw[p + 2], s3 = csr_sw[p + 3];
        float c0 = dn * dinv[s0.x] * __int_as_float(s0.y);
        float c1 = dn * dinv[s1.x] * __int_as_float(s1.y);
        float c2 = dn * dinv[s2.x] * __int_as_float(s2.y);
        float c3 = dn * dinv[s3.x] * __int_as_float(s3.y);
        acc += c0 * h2[(ll)s0.x * 16 + lane];
        acc += c1 * h2[(ll)s1.x * 16 + lane];
        acc += c2 * h2[(ll)s2.x * 16 + lane];
        acc += c3 * h2[(ll)s3.x * 16 + lane];
    }
    for (; p < pe; p++) {
        int2 s = csr_sw[p];
        acc += dn * dinv[s.x] * __int_as_float(s.y) * h2[(ll)s.x * 16 + lane];
    }
    float v = acc + b2[lane];
    float mx = v;
    for (int m = 1; m < 16; m <<= 1) mx = fmaxf(mx, __shfl_xor(mx, m, 16));
    float ex = expf(v - mx);
    float sum = ex;
    for (int m = 1; m < 16; m <<= 1) sum += __shfl_xor(sum, m, 16);
    out[(ll)node * 16 + lane] = v - mx - logf(sum);
}

extern "C" void kernel_launch(void* const* d_in, const int* in_sizes, int n_in,
                              void* d_out, int out_size, void* d_ws, size_t ws_size,
                              hipStream_t stream) {
    const float* x   = (const float*)d_in[0];
    const int*   ei  = (const int*)d_in[1];
    const float* ew  = (const float*)d_in[2];
    const float* W1  = (const float*)d_in[3];
    const float* b1  = (const float*)d_in[4];
    const float* Wg  = (const float*)d_in[5];
    const float* Wih = (const float*)d_in[6];
    const float* Whh = (const float*)d_in[7];
    const float* bih = (const float*)d_in[8];
    const float* bhh = (const float*)d_in[9];
    const float* W2  = (const float*)d_in[10];
    const float* b2  = (const float*)d_in[11];

    const int N = in_sizes[0] / 512;   // 100000
    const ll  E = in_sizes[2];         // 3200000
    const int* row = ei;
    const int* col = ei + E;

    // ---- workspace carve ----
    char* base = (char*)d_ws;
    size_t off = 0;
    auto carveF = [&](ll n) { float* p = (float*)(base + off); off += (size_t)n * 4; return p; };
    auto carveI = [&](ll n) { int*   p = (int*)(base + off);   off += (size_t)n * 4; return p; };
    float* dinv    = carveF(N);
    float* bufA    = carveF((ll)N * 64);
    float* bufB    = carveF((ll)N * 64);
    float* xbuf    = carveF((ll)N * 64);
    int*   rank    = carveI(E);
    int2*  csr_sw  = (int2*)(base + off); off += (size_t)E * 8;
    int*   row_st  = carveI(N + 1);
    int*   cnt     = carveI(N);
    int*   blkSums = carveI(512);
    int*   blkOff  = carveI(512);
    float* WihT    = carveF(12288);
    float* WhhT    = carveF(12288);
    (void)ws_size;

    const int B = 256;
    const int NB = (N + 255) / 256;

    // ---- CSR build (1 atomic/edge) + deg/dinv from CSR ----
    fill_i_kernel<<<(N + B - 1) / B, B, 0, stream>>>(cnt, 0, N);
    hist_rank_kernel<<<(int)((E + B - 1) / B), B, 0, stream>>>(col, cnt, rank, E);
    scanA_kernel<<<NB, 256, 0, stream>>>(cnt, blkSums, N);
    scanB_kernel<<<1, 512, 0, stream>>>(blkSums, blkOff, NB);
    scanC_kernel<<<NB, 256, 0, stream>>>(cnt, blkOff, row_st, N, (int)E);
    place_kernel<<<(int)((E + B - 1) / B), B, 0, stream>>>(row, col, ew, rank, row_st, csr_sw, E);
    deg_kernel<<<(N + B - 1) / B, B, 0, stream>>>(csr_sw, row_st, dinv, N);
    dinv_kernel<<<(N + B - 1) / B, B, 0, stream>>>(dinv, N);
    wtrans_kernel<<<(24576 + B - 1) / B, B, 0, stream>>>(Wih, Whh, WihT, WhhT);

    // ---- GCN conv 1 ----
    gemm_tile<512><<<(N + 127) / 128, 128, 0, stream>>>(x, W1, bufA, N);
    gather64_gcn1_kernel<<<(N + 3) / 4, 256, 0, stream>>>(csr_sw, row_st, bufA, dinv, b1, xbuf, N);

    // ---- 2x GatedGraphConv ----
    for (int l = 0; l < 2; l++) {
        gemm_tile<64><<<(N + 127) / 128, 128, 0, stream>>>(xbuf, Wg + (ll)l * 64 * 64, bufA, N);
        gather64_kernel<<<(N + 3) / 4, 256, 0, stream>>>(csr_sw, row_st, bufA, bufB, N);
        gru_fused_kernel<<<(N + 63) / 64, 256, 0, stream>>>(xbuf, bufB, WihT, WhhT, bih, bhh, N);
    }

    // ---- GCN conv 2 + log_softmax ----
    gemm_w2_kernel<<<(int)(((ll)N * 16 + B - 1) / B), B, 0, stream>>>(xbuf, W2, bufA, N);
    gather16_final_kernel<<<(N + 15) / 16, 256, 0, stream>>>(csr_sw, row_st, bufA, dinv, b2,
                                                             (float*)d_out, N);
}

// Round 6
// 1314.453 us; speedup vs baseline: 7.7768x; 1.0173x over previous
//
#include <hip/hip_runtime.h>
#include <hip/hip_bf16.h>

typedef long long ll;

// ---------------- fills ----------------
__global__ void fill_i_kernel(int* __restrict__ p, int v, ll n) {
    ll i = (ll)blockIdx.x * blockDim.x + threadIdx.x;
    if (i < n) p[i] = v;
}

// ---------------- hist+rank: rank[e] = cnt[col[e]]++  (ONE atomic per edge) ----------------
__global__ void hist_rank_kernel(const int* __restrict__ col, int* cnt,
                                 int* __restrict__ rank, ll E) {
    ll e = (ll)blockIdx.x * blockDim.x + threadIdx.x;
    if (e < E) rank[e] = atomicAdd(&cnt[col[e]], 1);
}

// ---------------- scan A: per-block sums of cnt ----------------
__global__ void scanA_kernel(const int* __restrict__ cnt, int* __restrict__ blockSums, int N) {
    __shared__ int s[256];
    int tid = threadIdx.x;
    int i = blockIdx.x * 256 + tid;
    s[tid] = (i < N) ? cnt[i] : 0;
    __syncthreads();
    for (int off = 128; off > 0; off >>= 1) {
        if (tid < off) s[tid] += s[tid + off];
        __syncthreads();
    }
    if (tid == 0) blockSums[blockIdx.x] = s[0];
}

// ---------------- scan B: exclusive scan of blockSums (single block, 512 thr) ----------------
__global__ void scanB_kernel(const int* __restrict__ blockSums, int* __restrict__ blockOff, int NB) {
    __shared__ int s[512];
    int tid = threadIdx.x;
    int v = (tid < NB) ? blockSums[tid] : 0;
    s[tid] = v;
    __syncthreads();
    for (int off = 1; off < 512; off <<= 1) {
        int t = (tid >= off) ? s[tid - off] : 0;
        __syncthreads();
        s[tid] += t;
        __syncthreads();
    }
    if (tid < NB) blockOff[tid] = s[tid] - v;  // exclusive
}

// ---------------- scan C: row_start = blockOff + excl-scan within block ----------------
__global__ void scanC_kernel(const int* __restrict__ cnt, const int* __restrict__ blockOff,
                             int* __restrict__ row_start, int N, int E) {
    __shared__ int s[256];
    int tid = threadIdx.x;
    int i = blockIdx.x * 256 + tid;
    int v = (i < N) ? cnt[i] : 0;
    s[tid] = v;
    __syncthreads();
    for (int off = 1; off < 256; off <<= 1) {
        int t = (tid >= off) ? s[tid - off] : 0;
        __syncthreads();
        s[tid] += t;
        __syncthreads();
    }
    if (i < N) row_start[i] = s[tid] - v + blockOff[blockIdx.x];
    if (i == N) row_start[N] = E;
}

// ---------------- placement (no atomics): csr_sw[row_st[col]+rank] = {src, bits(w)} ----------------
__global__ void place_kernel(const int* __restrict__ row, const int* __restrict__ col,
                             const float* __restrict__ ew, const int* __restrict__ rank,
                             const int* __restrict__ row_st, int2* __restrict__ csr_sw, ll E) {
    ll e = (ll)blockIdx.x * blockDim.x + threadIdx.x;
    if (e >= E) return;
    int c = col[e];
    int pos = row_st[c] + rank[e];
    csr_sw[pos] = make_int2(row[e], __float_as_int(ew[e]));
}

// ---------------- deg from CSR (no atomics): deg[n] = 1 + sum w ----------------
__global__ void deg_kernel(const int2* __restrict__ csr_sw, const int* __restrict__ row_st,
                           float* __restrict__ deg, int N) {
    int n = blockIdx.x * blockDim.x + threadIdx.x;
    if (n >= N) return;
    int p = row_st[n], pe = row_st[n + 1];
    float d = 1.0f;  // self-loop weight
    for (; p < pe; p++) d += __int_as_float(csr_sw[p].y);
    deg[n] = d;
}

// ---------------- dinv = 1/sqrt(deg) (in place) ----------------
__global__ void dinv_kernel(float* __restrict__ deg, int N) {
    int i = blockIdx.x * blockDim.x + threadIdx.x;
    if (i < N) {
        float d = deg[i];
        deg[i] = d > 0.0f ? 1.0f / sqrtf(d) : 0.0f;
    }
}

// ---------------- weight transpose: WT[k*192+j] = W[j*64+k], W is [192,64] ----------------
// NOTE: 12288 is NOT a power of two -> subtraction, not &12287 (R3 bug).
__global__ void wtrans_kernel(const float* __restrict__ Wih, const float* __restrict__ Whh,
                              float* __restrict__ WihT, float* __restrict__ WhhT) {
    int t = blockIdx.x * blockDim.x + threadIdx.x;  // 0..24575
    if (t >= 24576) return;
    int half = (t >= 12288) ? 1 : 0;
    int i = t - half * 12288;
    const float* src = half ? Whh : Wih;
    float* dst = half ? WhhT : WihT;
    int k = i / 192;
    int j = i - k * 192;
    dst[i] = src[j * 64 + k];
}

// ---------------- tiled GEMM: C[N,64] = A[N,K] @ B[K,64] ----------------
// R6: 256 thr/block (4 waves, was 2) for latency hiding; thread tile 4x8 (32 acc,
// ~64 VGPR); As padded [16][132] -> staging writes spread banks, b128 reads stay
// 16B-aligned & conflict-free. Evidence: R5 VALUBusy 33%, Occupancy 12.7%.
template <int K>
__global__ __launch_bounds__(256) void gemm_tile(const float* __restrict__ A,
                                                 const float* __restrict__ B,
                                                 float* __restrict__ C, int N) {
    const int BM = 128, BK = 16;
    __shared__ float As[BK][132];   // +4 pad
    __shared__ float Bs[BK][64];
    int tid = threadIdx.x;
    int bm = blockIdx.x * BM;
    int tx = tid & 7;    // col group: cols tx*8..+7
    int ty = tid >> 3;   // 0..31: rows ty*4..+3
    int lr = tid >> 2;   // A loader: row 0..63 (two passes)
    int lc = tid & 3;    // A loader: k-chunk
    int br = tid >> 4;   // B loader: k row 0..15
    int bc = tid & 15;   // B loader: col chunk

    float acc[4][8];
#pragma unroll
    for (int i = 0; i < 4; i++)
#pragma unroll
        for (int j = 0; j < 8; j++) acc[i][j] = 0.0f;

    for (int k0 = 0; k0 < K; k0 += BK) {
        // A tile 128x16 -> transposed into As
#pragma unroll
        for (int rr = 0; rr < 2; rr++) {
            int r = lr + rr * 64;
            int gr = bm + r;
            gr = gr < N ? gr : N - 1;
            const float4 av = *(const float4*)&A[(ll)gr * K + k0 + lc * 4];
            As[lc * 4 + 0][r] = av.x;
            As[lc * 4 + 1][r] = av.y;
            As[lc * 4 + 2][r] = av.z;
            As[lc * 4 + 3][r] = av.w;
        }
        // B tile 16x64: one float4 per thread
        *(float4*)&Bs[br][bc * 4] = *(const float4*)&B[(ll)(k0 + br) * 64 + bc * 4];
        __syncthreads();
#pragma unroll
        for (int k = 0; k < BK; k++) {
            float4 a = *(const float4*)&As[k][ty * 4];
            float4 b0 = *(const float4*)&Bs[k][tx * 8];
            float4 b1 = *(const float4*)&Bs[k][tx * 8 + 4];
            float av[4] = {a.x, a.y, a.z, a.w};
            float bv[8] = {b0.x, b0.y, b0.z, b0.w, b1.x, b1.y, b1.z, b1.w};
#pragma unroll
            for (int i = 0; i < 4; i++)
#pragma unroll
                for (int j = 0; j < 8; j++) acc[i][j] += av[i] * bv[j];
        }
        __syncthreads();
    }
#pragma unroll
    for (int i = 0; i < 4; i++) {
        int gr = bm + ty * 4 + i;
        if (gr < N) {
            float4 v0 = make_float4(acc[i][0], acc[i][1], acc[i][2], acc[i][3]);
            float4 v1 = make_float4(acc[i][4], acc[i][5], acc[i][6], acc[i][7]);
            *(float4*)&C[(ll)gr * 64 + tx * 8] = v0;
            *(float4*)&C[(ll)gr * 64 + tx * 8 + 4] = v1;
        }
    }
}

// ---------------- gather64 + GCN1 epilogue (norm computed on the fly) ----------------
__global__ __launch_bounds__(256) void gather64_gcn1_kernel(
    const int2* __restrict__ csr_sw, const int* __restrict__ row_start,
    const float* __restrict__ h1, const float* __restrict__ dinv,
    const float* __restrict__ b1, float* __restrict__ xbuf, int N) {
    int node = blockIdx.x * 4 + (threadIdx.x >> 6);
    if (node >= N) return;
    int lane = threadIdx.x & 63;
    int p = row_start[node], pe = row_start[node + 1];
    float dn = dinv[node];
    float acc = dn * dn * h1[(ll)node * 64 + lane];
    for (; p + 4 <= pe; p += 4) {
        int2 s0 = csr_sw[p], s1 = csr_sw[p + 1], s2 = csr_sw[p + 2], s3 = csr_sw[p + 3];
        float c0 = dn * dinv[s0.x] * __int_as_float(s0.y);
        float c1 = dn * dinv[s1.x] * __int_as_float(s1.y);
        float c2 = dn * dinv[s2.x] * __int_as_float(s2.y);
        float c3 = dn * dinv[s3.x] * __int_as_float(s3.y);
        acc += c0 * h1[(ll)s0.x * 64 + lane];
        acc += c1 * h1[(ll)s1.x * 64 + lane];
        acc += c2 * h1[(ll)s2.x * 64 + lane];
        acc += c3 * h1[(ll)s3.x * 64 + lane];
    }
    for (; p < pe; p++) {
        int2 s = csr_sw[p];
        acc += dn * dinv[s.x] * __int_as_float(s.y) * h1[(ll)s.x * 64 + lane];
    }
    float v = acc + b1[lane];
    xbuf[(ll)node * 64 + lane] = v > 0.0f ? v : 0.0f;
}

// ---------------- plain gather64 (GGC agg) ----------------
__global__ __launch_bounds__(256) void gather64_kernel(
    const int2* __restrict__ csr_sw, const int* __restrict__ row_start,
    const float* __restrict__ src, float* __restrict__ dst, int N) {
    int node = blockIdx.x * 4 + (threadIdx.x >> 6);
    if (node >= N) return;
    int lane = threadIdx.x & 63;
    int p = row_start[node], pe = row_start[node + 1];
    float acc = 0.0f;
    for (; p + 4 <= pe; p += 4) {
        int2 s0 = csr_sw[p], s1 = csr_sw[p + 1], s2 = csr_sw[p + 2], s3 = csr_sw[p + 3];
        acc += __int_as_float(s0.y) * src[(ll)s0.x * 64 + lane];
        acc += __int_as_float(s1.y) * src[(ll)s1.x * 64 + lane];
        acc += __int_as_float(s2.y) * src[(ll)s2.x * 64 + lane];
        acc += __int_as_float(s3.y) * src[(ll)s3.x * 64 + lane];
    }
    for (; p < pe; p++) {
        int2 s = csr_sw[p];
        acc += __int_as_float(s.y) * src[(ll)s.x * 64 + lane];
    }
    dst[(ll)node * 64 + lane] = acc;
}

// ---------------- fused GRU (unchanged from R4) ----------------
__global__ __launch_bounds__(256) void gru_fused_kernel(
    float* __restrict__ x, const float* __restrict__ agg,
    const float* __restrict__ WihT, const float* __restrict__ WhhT,
    const float* __restrict__ bih, const float* __restrict__ bhh, int N) {
    __shared__ float Aag[16][64];
    __shared__ float Axx[16][64];
    __shared__ float Bih[16][192];
    __shared__ float Bhh[16][192];

    int tid = threadIdx.x;
    int bm = blockIdx.x * 64;
    int rg = tid >> 5;
    int cg = tid & 31;
    int jb = cg * 2;
    int lm = tid >> 2;
    int lkc = tid & 3;

    float air[2][8], aiz[2][8], ain[2][8], ahr[2][8], ahz[2][8], ahn[2][8];
#pragma unroll
    for (int j = 0; j < 2; j++)
#pragma unroll
        for (int i = 0; i < 8; i++) {
            air[j][i] = 0.f; aiz[j][i] = 0.f; ain[j][i] = 0.f;
            ahr[j][i] = 0.f; ahz[j][i] = 0.f; ahn[j][i] = 0.f;
        }

    for (int kb = 0; kb < 4; kb++) {
        int k0 = kb * 16;
        int gr = bm + lm; gr = gr < N ? gr : N - 1;
        float4 va = *(const float4*)&agg[(ll)gr * 64 + k0 + lkc * 4];
        float4 vx = *(const float4*)&x[(ll)gr * 64 + k0 + lkc * 4];
        Aag[lkc * 4 + 0][lm] = va.x; Aag[lkc * 4 + 1][lm] = va.y;
        Aag[lkc * 4 + 2][lm] = va.z; Aag[lkc * 4 + 3][lm] = va.w;
        Axx[lkc * 4 + 0][lm] = vx.x; Axx[lkc * 4 + 1][lm] = vx.y;
        Axx[lkc * 4 + 2][lm] = vx.z; Axx[lkc * 4 + 3][lm] = vx.w;
#pragma unroll
        for (int p = 0; p < 3; p++) {
            int f = tid + p * 256;
            int br = f / 48, bc = f - br * 48;
            *(float4*)&Bih[br][bc * 4] = *(const float4*)&WihT[(ll)(k0 + br) * 192 + bc * 4];
            *(float4*)&Bhh[br][bc * 4] = *(const float4*)&WhhT[(ll)(k0 + br) * 192 + bc * 4];
        }
        __syncthreads();
#pragma unroll
        for (int k = 0; k < 16; k++) {
            float4 g0 = *(const float4*)&Aag[k][rg * 8];
            float4 g1 = *(const float4*)&Aag[k][rg * 8 + 4];
            float4 x0 = *(const float4*)&Axx[k][rg * 8];
            float4 x1 = *(const float4*)&Axx[k][rg * 8 + 4];
            float2 wir = *(const float2*)&Bih[k][jb];
            float2 wiz = *(const float2*)&Bih[k][64 + jb];
            float2 win = *(const float2*)&Bih[k][128 + jb];
            float2 whr = *(const float2*)&Bhh[k][jb];
            float2 whz = *(const float2*)&Bhh[k][64 + jb];
            float2 whn = *(const float2*)&Bhh[k][128 + jb];
            float ag[8] = {g0.x, g0.y, g0.z, g0.w, g1.x, g1.y, g1.z, g1.w};
            float ax[8] = {x0.x, x0.y, x0.z, x0.w, x1.x, x1.y, x1.z, x1.w};
#pragma unroll
            for (int i = 0; i < 8; i++) {
                air[0][i] += ag[i] * wir.x; air[1][i] += ag[i] * wir.y;
                aiz[0][i] += ag[i] * wiz.x; aiz[1][i] += ag[i] * wiz.y;
                ain[0][i] += ag[i] * win.x; ain[1][i] += ag[i] * win.y;
                ahr[0][i] += ax[i] * whr.x; ahr[1][i] += ax[i] * whr.y;
                ahz[0][i] += ax[i] * whz.x; ahz[1][i] += ax[i] * whz.y;
                ahn[0][i] += ax[i] * whn.x; ahn[1][i] += ax[i] * whn.y;
            }
        }
        __syncthreads();
    }

    float bi_r0 = bih[jb], bi_r1 = bih[jb + 1];
    float bi_z0 = bih[64 + jb], bi_z1 = bih[64 + jb + 1];
    float bi_n0 = bih[128 + jb], bi_n1 = bih[128 + jb + 1];
    float bh_r0 = bhh[jb], bh_r1 = bhh[jb + 1];
    float bh_z0 = bhh[64 + jb], bh_z1 = bhh[64 + jb + 1];
    float bh_n0 = bhh[128 + jb], bh_n1 = bhh[128 + jb + 1];
#pragma unroll
    for (int i = 0; i < 8; i++) {
        int node = bm + rg * 8 + i;
        if (node >= N) break;
        float2 xo = *(const float2*)&x[(ll)node * 64 + jb];
        float r0 = 1.f / (1.f + expf(-(air[0][i] + bi_r0 + ahr[0][i] + bh_r0)));
        float z0 = 1.f / (1.f + expf(-(aiz[0][i] + bi_z0 + ahz[0][i] + bh_z0)));
        float n0 = tanhf(ain[0][i] + bi_n0 + r0 * (ahn[0][i] + bh_n0));
        float r1 = 1.f / (1.f + expf(-(air[1][i] + bi_r1 + ahr[1][i] + bh_r1)));
        float z1 = 1.f / (1.f + expf(-(aiz[1][i] + bi_z1 + ahz[1][i] + bh_z1)));
        float n1 = tanhf(ain[1][i] + bi_n1 + r1 * (ahn[1][i] + bh_n1));
        float2 xn;
        xn.x = (1.f - z0) * n0 + z0 * xo.x;
        xn.y = (1.f - z1) * n1 + z1 * xo.y;
        *(float2*)&x[(ll)node * 64 + jb] = xn;
    }
}

// ---------------- h2 = x @ W2 ([N,64]@[64,16]) ----------------
__global__ void gemm_w2_kernel(const float* __restrict__ x, const float* __restrict__ W2,
                               float* __restrict__ h2, int N) {
    ll t = (ll)blockIdx.x * blockDim.x + threadIdx.x;
    if (t >= (ll)N * 16) return;
    int n = (int)(t >> 4);
    int c = (int)(t & 15);
    float acc = 0.0f;
#pragma unroll
    for (int k = 0; k < 64; k++) acc += x[(ll)n * 64 + k] * W2[k * 16 + c];
    h2[t] = acc;
}

// ---------------- gather16 + self-loop + bias + log_softmax (norm on the fly) ----------------
__global__ __launch_bounds__(256) void gather16_final_kernel(
    const int2* __restrict__ csr_sw, const int* __restrict__ row_start,
    const float* __restrict__ h2, const float* __restrict__ dinv,
    const float* __restrict__ b2, float* __restrict__ out, int N) {
    int node = blockIdx.x * 16 + (threadIdx.x >> 4);
    if (node >= N) return;
    int lane = threadIdx.x & 15;
    int p = row_start[node], pe = row_start[node + 1];
    float dn = dinv[node];
    float acc = dn * dn * h2[(ll)node * 16 + lane];
    for (; p + 4 <= pe; p += 4) {
        int2 s0 = csr_sw[p], s1 = csr_sw[p + 1], s2 = csr_sw[p + 2], s3 = csr_sw[p + 3];
        float c0 = dn * dinv[s0.x] * __int_as_float(s0.y);
        float c1 = dn * dinv[s1.x] * __int_as_float(s1.y);
        float c2 = dn * dinv[s2.x] * __int_as_float(s2.y);
        float c3 = dn * dinv[s3.x] * __int_as_float(s3.y);
        acc += c0 * h2[(ll)s0.x * 16 + lane];
        acc += c1 * h2[(ll)s1.x * 16 + lane];
        acc += c2 * h2[(ll)s2.x * 16 + lane];
        acc += c3 * h2[(ll)s3.x * 16 + lane];
    }
    for (; p < pe; p++) {
        int2 s = csr_sw[p];
        acc += dn * dinv[s.x] * __int_as_float(s.y) * h2[(ll)s.x * 16 + lane];
    }
    float v = acc + b2[lane];
    float mx = v;
    for (int m = 1; m < 16; m <<= 1) mx = fmaxf(mx, __shfl_xor(mx, m, 16));
    float ex = expf(v - mx);
    float sum = ex;
    for (int m = 1; m < 16; m <<= 1) sum += __shfl_xor(sum, m, 16);
    out[(ll)node * 16 + lane] = v - mx - logf(sum);
}

extern "C" void kernel_launch(void* const* d_in, const int* in_sizes, int n_in,
                              void* d_out, int out_size, void* d_ws, size_t ws_size,
                              hipStream_t stream) {
    const float* x   = (const float*)d_in[0];
    const int*   ei  = (const int*)d_in[1];
    const float* ew  = (const float*)d_in[2];
    const float* W1  = (const float*)d_in[3];
    const float* b1  = (const float*)d_in[4];
    const float* Wg  = (const float*)d_in[5];
    const float* Wih = (const float*)d_in[6];
    const float* Whh = (const float*)d_in[7];
    const float* bih = (const float*)d_in[8];
    const float* bhh = (const float*)d_in[9];
    const float* W2  = (const float*)d_in[10];
    const float* b2  = (const float*)d_in[11];

    const int N = in_sizes[0] / 512;   // 100000
    const ll  E = in_sizes[2];         // 3200000
    const int* row = ei;
    const int* col = ei + E;

    // ---- workspace carve ----
    char* base = (char*)d_ws;
    size_t off = 0;
    auto carveF = [&](ll n) { float* p = (float*)(base + off); off += (size_t)n * 4; return p; };
    auto carveI = [&](ll n) { int*   p = (int*)(base + off);   off += (size_t)n * 4; return p; };
    float* dinv    = carveF(N);
    float* bufA    = carveF((ll)N * 64);
    float* bufB    = carveF((ll)N * 64);
    float* xbuf    = carveF((ll)N * 64);
    int*   rank    = carveI(E);
    int2*  csr_sw  = (int2*)(base + off); off += (size_t)E * 8;
    int*   row_st  = carveI(N + 1);
    int*   cnt     = carveI(N);
    int*   blkSums = carveI(512);
    int*   blkOff  = carveI(512);
    float* WihT    = carveF(12288);
    float* WhhT    = carveF(12288);
    (void)ws_size;

    const int B = 256;
    const int NB = (N + 255) / 256;

    // ---- CSR build (1 atomic/edge) + deg/dinv from CSR ----
    fill_i_kernel<<<(N + B - 1) / B, B, 0, stream>>>(cnt, 0, N);
    hist_rank_kernel<<<(int)((E + B - 1) / B), B, 0, stream>>>(col, cnt, rank, E);
    scanA_kernel<<<NB, 256, 0, stream>>>(cnt, blkSums, N);
    scanB_kernel<<<1, 512, 0, stream>>>(blkSums, blkOff, NB);
    scanC_kernel<<<NB, 256, 0, stream>>>(cnt, blkOff, row_st, N, (int)E);
    place_kernel<<<(int)((E + B - 1) / B), B, 0, stream>>>(row, col, ew, rank, row_st, csr_sw, E);
    deg_kernel<<<(N + B - 1) / B, B, 0, stream>>>(csr_sw, row_st, dinv, N);
    dinv_kernel<<<(N + B - 1) / B, B, 0, stream>>>(dinv, N);
    wtrans_kernel<<<(24576 + B - 1) / B, B, 0, stream>>>(Wih, Whh, WihT, WhhT);

    // ---- GCN conv 1 ----
    gemm_tile<512><<<(N + 127) / 128, 256, 0, stream>>>(x, W1, bufA, N);
    gather64_gcn1_kernel<<<(N + 3) / 4, 256, 0, stream>>>(csr_sw, row_st, bufA, dinv, b1, xbuf, N);

    // ---- 2x GatedGraphConv ----
    for (int l = 0; l < 2; l++) {
        gemm_tile<64><<<(N + 127) / 128, 256, 0, stream>>>(xbuf, Wg + (ll)l * 64 * 64, bufA, N);
        gather64_kernel<<<(N + 3) / 4, 256, 0, stream>>>(csr_sw, row_st, bufA, bufB, N);
        gru_fused_kernel<<<(N + 63) / 64, 256, 0, stream>>>(xbuf, bufB, WihT, WhhT, bih, bhh, N);
    }

    // ---- GCN conv 2 + log_softmax ----
    gemm_w2_kernel<<<(int)(((ll)N * 16 + B - 1) / B), B, 0, stream>>>(xbuf, W2, bufA, N);
    gather16_final_kernel<<<(N + 15) / 16, 256, 0, stream>>>(csr_sw, row_st, bufA, dinv, b2,
                                                             (float*)d_out, N);
}